// Round 13
// baseline (196.849 us; speedup 1.0000x reference)
//
#include <hip/hip_runtime.h>

#define DM 128
#define DFF 512
#define CLAMP_V 5.0f
#define LN_EPS 1e-5f

typedef __attribute__((ext_vector_type(8))) short bf16x8;
typedef __attribute__((ext_vector_type(4))) float f32x4;

__device__ __forceinline__ float b2f(ushort u) {
  union { uint u; float f; } x; x.u = ((uint)u) << 16; return x.f;
}
__device__ __forceinline__ ushort f2b(float f) {
  union { float f; uint u; } x; x.f = f;
  uint r = x.u + 0x7FFFu + ((x.u >> 16) & 1u);
  return (ushort)(r >> 16);
}
__device__ __forceinline__ void unpackw(uint w, float& lo, float& hi) {
  union { uint u; float f; } A, B;
  A.u = w << 16; B.u = w & 0xFFFF0000u;
  lo = A.f; hi = B.f;
}
__device__ __forceinline__ void unpack8w(uint4 w, float* o) {
  unpackw(w.x, o[0], o[1]); unpackw(w.y, o[2], o[3]);
  unpackw(w.z, o[4], o[5]); unpackw(w.w, o[6], o[7]);
}

// ---------------- fused prep: feat cast + weight cast + degree count ----------------
__global__ void k_prep(const float* __restrict__ feat,
                       const float* __restrict__ wq, const float* __restrict__ wk,
                       const float* __restrict__ wv, const float* __restrict__ wo,
                       const float* __restrict__ w1, const float* __restrict__ w2,
                       ushort* __restrict__ feat_bf, ushort* __restrict__ wbf,
                       const int* __restrict__ dst, int* __restrict__ deg,
                       int nf4, int castBlocks, int E) {
  if ((int)blockIdx.x >= castBlocks) {
    int e = ((int)blockIdx.x - castBlocks) * 256 + threadIdx.x;
    if (e < E) atomicAdd(&deg[dst[e]], 1);
    return;
  }
  int i = blockIdx.x * 256 + threadIdx.x;
  if (i < nf4) {
    float4 v = *reinterpret_cast<const float4*>(feat + i * 4);
    ushort4 o; o.x = f2b(v.x); o.y = f2b(v.y); o.z = f2b(v.z); o.w = f2b(v.w);
    *reinterpret_cast<ushort4*>(feat_bf + i * 4) = o;
    return;
  }
  int i4 = (i - nf4) * 4;
  if (i4 >= 196608) return;
  const float* s; int o;
  if      (i4 < 16384)  { s = wq; o = i4; }
  else if (i4 < 32768)  { s = wk; o = i4 - 16384; }
  else if (i4 < 49152)  { s = wv; o = i4 - 32768; }
  else if (i4 < 65536)  { s = wo; o = i4 - 49152; }
  else if (i4 < 131072) { s = w1; o = i4 - 65536; }
  else                  { s = w2; o = i4 - 131072; }
  float4 v = *reinterpret_cast<const float4*>(s + o);
  ushort4 u; u.x = f2b(v.x); u.y = f2b(v.y); u.z = f2b(v.z); u.w = f2b(v.w);
  *reinterpret_cast<ushort4*>(wbf + i4) = u;
}

#define SC_EPB 1024

// single-kernel exclusive scan: block brute-force sums prior degs, then local
// scan; also zeroes cur and writes off[n]=E.
__global__ __launch_bounds__(256) void k_scan(const int* __restrict__ deg,
                                              int* __restrict__ off,
                                              int* __restrict__ cur,
                                              int n, int E) {
  __shared__ int sh[256];
  __shared__ int wsum[4];
  const int t = threadIdx.x;
  const int bstart = blockIdx.x * SC_EPB;

  int gs = 0;
  for (int base = t * 4; base < bstart; base += SC_EPB) {
    int4 v = *reinterpret_cast<const int4*>(deg + base);
    gs += v.x + v.y + v.z + v.w;
  }
  #pragma unroll
  for (int m = 1; m < 64; m <<= 1) gs += __shfl_xor(gs, m);
  if ((t & 63) == 0) wsum[t >> 6] = gs;
  __syncthreads();
  int gadd = wsum[0] + wsum[1] + wsum[2] + wsum[3];
  __syncthreads();

  int base = bstart + t * 4;
  int4 v = {0, 0, 0, 0};
  if (base + 3 < n) {
    v = *reinterpret_cast<const int4*>(deg + base);
  } else {
    if (base     < n) v.x = deg[base];
    if (base + 1 < n) v.y = deg[base + 1];
    if (base + 2 < n) v.z = deg[base + 2];
    if (base + 3 < n) v.w = deg[base + 3];
  }
  int s = v.x + v.y + v.z + v.w;
  sh[t] = s;
  __syncthreads();
  #pragma unroll
  for (int d = 1; d < 256; d <<= 1) {
    int x = 0;
    if (t >= d) x = sh[t - d];
    __syncthreads();
    sh[t] += x;
    __syncthreads();
  }
  int ex = sh[t] - s + gadd;
  if (base + 3 < n) {
    int4 o; o.x = ex; o.y = ex + v.x; o.z = ex + v.x + v.y; o.w = ex + v.x + v.y + v.z;
    *reinterpret_cast<int4*>(off + base) = o;
    int4 z = {0, 0, 0, 0};
    *reinterpret_cast<int4*>(cur + base) = z;
  } else {
    if (base     < n) { off[base]     = ex;                    cur[base]     = 0; }
    if (base + 1 < n) { off[base + 1] = ex + v.x;              cur[base + 1] = 0; }
    if (base + 2 < n) { off[base + 2] = ex + v.x + v.y;        cur[base + 2] = 0; }
    if (base + 3 < n) { off[base + 3] = ex + v.x + v.y + v.z;  cur[base + 3] = 0; }
  }
  if (blockIdx.x == 0 && t == 0) off[n] = E;
}

__global__ void k_scatter(const int* __restrict__ src, const int* __restrict__ dst,
                          const int* __restrict__ off, int* __restrict__ cur,
                          int* __restrict__ csr, int E) {
  int e = blockIdx.x * blockDim.x + threadIdx.x;
  if (e < E) {
    int d = dst[e];
    int p = off[d] + atomicAdd(&cur[d], 1);
    csr[p] = src[e];
  }
}

// =====================================================================
// k_mmT: one-tile-per-block GEMM for K=128 (round-8 proven). Used for
// qkv only (FLAGS=0, QKV split output). 512 thr, 8 waves (2x4 of 64x32).
// =====================================================================
template<int FLAGS>
__global__ __launch_bounds__(512, 2) void k_mmT(
    const ushort* __restrict__ A, const ushort* __restrict__ W,
    ushort* __restrict__ Cb, ushort* __restrict__ Cb2, int M)
{
  __shared__ ushort As[128 * 128];
  __shared__ ushort Bs[128 * 128];

  const int tid = threadIdx.x;
  const int wv = tid >> 6, ln = tid & 63;
  const int bnb = blockIdx.x;
  const int mbase = blockIdx.y * 128;
  const int wrow = (wv >> 2) * 64, wcol = (wv & 3) * 32;
  const int o_base = tid * 16;

  #pragma unroll
  for (int is = 0; is < 4; ++is) {
    int o = is * 8192 + o_base;
    int row = o >> 8;
    int c = ((o >> 4) & 15) ^ (row & 15);
    int gr = min(mbase + row, M - 1);
    const ushort* sA = A + (size_t)gr * 128 + c * 8;
    __builtin_amdgcn_global_load_lds(
        (const __attribute__((address_space(1))) void*)sA,
        (__attribute__((address_space(3))) void*)((char*)As + is * 8192 + wv * 1024),
        16, 0, 0);
    const ushort* sB = W + (size_t)(bnb * 128 + row) * 128 + c * 8;
    __builtin_amdgcn_global_load_lds(
        (const __attribute__((address_space(1))) void*)sB,
        (__attribute__((address_space(3))) void*)((char*)Bs + is * 8192 + wv * 1024),
        16, 0, 0);
  }
  __syncthreads();

  f32x4 acc[4][2] = {};
  const char* AsB = (const char*)As;
  const char* BsB = (const char*)Bs;
  #pragma unroll
  for (int kk = 0; kk < 4; ++kk) {
    bf16x8 af[4], bfr[2];
    #pragma unroll
    for (int m = 0; m < 4; ++m) {
      int r = wrow + m * 16 + (ln & 15);
      int c = kk * 4 + (ln >> 4);
      af[m] = *reinterpret_cast<const bf16x8*>(AsB + r * 256 + ((c ^ (r & 15)) << 4));
    }
    #pragma unroll
    for (int n = 0; n < 2; ++n) {
      int r = wcol + n * 16 + (ln & 15);
      int c = kk * 4 + (ln >> 4);
      bfr[n] = *reinterpret_cast<const bf16x8*>(BsB + r * 256 + ((c ^ (r & 15)) << 4));
    }
    #pragma unroll
    for (int m = 0; m < 4; ++m)
      #pragma unroll
      for (int n = 0; n < 2; ++n)
        acc[m][n] = __builtin_amdgcn_mfma_f32_16x16x32_bf16(af[m], bfr[n], acc[m][n], 0, 0, 0);
  }

  #pragma unroll
  for (int m = 0; m < 4; ++m) {
    int gr0 = mbase + wrow + m * 16 + (ln >> 4) * 4;
    #pragma unroll
    for (int n = 0; n < 2; ++n) {
      int gcl = wcol + n * 16 + (ln & 15);
      #pragma unroll
      for (int r = 0; r < 4; ++r) {
        int gr = gr0 + r;
        if (gr >= M) continue;
        float v = acc[m][n][r];
        if (bnb == 0) Cb[(size_t)gr * 128 + gcl] = f2b(v);
        else          Cb2[(size_t)gr * 256 + (bnb - 1) * 128 + gcl] = f2b(v);
      }
    }
  }
}

// =====================================================================
// k_fused: wo-GEMM + LN1 + ffn1 + ffn2 + LN2 per 64-row block.
// LDS: mid 64KB (M0 h1b | M1 sav | M2 W1-slot) + wbuf 2x32KB.
// h1 f32 lives in p0 registers across the whole kernel (no global h1).
// =====================================================================
__global__ __launch_bounds__(512, 2) void k_fused(
    const ushort* __restrict__ sav, const float* __restrict__ feat,
    const ushort* __restrict__ wo,
    const float* __restrict__ ln1g, const float* __restrict__ ln1b,
    const ushort* __restrict__ w1, const float* __restrict__ b1,
    const ushort* __restrict__ w2, const float* __restrict__ b2,
    const float* __restrict__ ln2g, const float* __restrict__ ln2b,
    float* __restrict__ outp, int M)
{
  __shared__ ushort mid[64 * 512];        // 64KB
  __shared__ ushort wbuf[2][128 * 128];   // 2 x 32KB

  const int tid = threadIdx.x;
  const int wv = tid >> 6, ln = tid & 63;
  const int lr = ln & 15, hi = ln >> 4;
  const int mbase = blockIdx.x * 64;
  char* M0 = (char*)mid;            // h1b [64][128]
  char* M1 = (char*)mid + 16384;    // sav [64][128]
  char* M2 = (char*)mid + 32768;    // W1 slot [128][128]

  auto STG128 = [&](const ushort* srcBase, int srcLd, int colOff, char* dstLds) {
    #pragma unroll
    for (int is = 0; is < 4; ++is) {
      int o = is * 8192 + tid * 16;
      int r = o >> 8;
      int c = ((o >> 4) & 15) ^ (r & 15);
      const ushort* s = srcBase + (size_t)r * srcLd + colOff + c * 8;
      __builtin_amdgcn_global_load_lds(
          (const __attribute__((address_space(1))) void*)s,
          (__attribute__((address_space(3))) void*)(dstLds + is * 8192 + wv * 1024),
          16, 0, 0);
    }
  };

  // ---- prologue: sav -> M1, Wo -> wbuf[0], W1g0 -> M2 ----
  #pragma unroll
  for (int is = 0; is < 2; ++is) {
    int o = is * 8192 + tid * 16;
    int r = o >> 8;
    int c = ((o >> 4) & 15) ^ (r & 15);
    int gr = min(mbase + r, M - 1);
    const ushort* s = sav + (size_t)gr * 128 + c * 8;
    __builtin_amdgcn_global_load_lds(
        (const __attribute__((address_space(1))) void*)s,
        (__attribute__((address_space(3))) void*)(M1 + is * 8192 + wv * 1024),
        16, 0, 0);
  }
  STG128(wo, 128, 0, (char*)wbuf[0]);
  STG128(w1, 128, 0, M2);
  __syncthreads();

  const int gc = wv * 16 + lr;

  // ---- ph0: x1 = sav @ Wo^T ----
  f32x4 p0[4] = {};
  {
    const char* wB = (const char*)wbuf[0];
    #pragma unroll
    for (int kk = 0; kk < 4; ++kk) {
      int c = kk * 4 + hi;
      int wr = wv * 16 + lr;
      bf16x8 bWo = *reinterpret_cast<const bf16x8*>(wB + wr * 256 + ((c ^ (wr & 15)) << 4));
      bf16x8 aS[4];
      #pragma unroll
      for (int m = 0; m < 4; ++m) {
        int r = m * 16 + lr;
        aS[m] = *reinterpret_cast<const bf16x8*>(M1 + r * 256 + ((c ^ (r & 15)) << 4));
      }
      #pragma unroll
      for (int m = 0; m < 4; ++m)
        p0[m] = __builtin_amdgcn_mfma_f32_16x16x32_bf16(aS[m], bWo, p0[m], 0, 0, 0);
    }
  }
  // +feat residual
  #pragma unroll
  for (int m = 0; m < 4; ++m)
    #pragma unroll
    for (int r = 0; r < 4; ++r) {
      int gr = mbase + m * 16 + hi * 4 + r;
      p0[m][r] += feat[(size_t)min(gr, M - 1) * 128 + gc];
    }
  // LN1 partials -> lnred (alias wbuf[1])
  float* lnred = reinterpret_cast<float*>(&wbuf[1][0]);
  #pragma unroll
  for (int m = 0; m < 4; ++m)
    #pragma unroll
    for (int r = 0; r < 4; ++r) {
      float sm = p0[m][r];
      float sq = p0[m][r] * p0[m][r];
      #pragma unroll
      for (int msk = 1; msk <= 8; msk <<= 1) {
        sm += __shfl_xor(sm, msk);
        sq += __shfl_xor(sq, msk);
      }
      if (lr == 0) {
        int row = m * 16 + hi * 4 + r;
        lnred[row * 16 + wv * 2]     = sm;
        lnred[row * 16 + wv * 2 + 1] = sq;
      }
    }
  __syncthreads();           // ph0 Wo reads done; lnred visible
  STG128(w1 + 16384, 128, 0, (char*)wbuf[0]);   // W1g1 (Wo dead)
  // normalize -> h1res (in p0), write h1b -> M0
  {
    float g1v = ln1g[gc], bb1 = ln1b[gc];
    int chunk = gc >> 3;
    int sub = (gc & 7) * 2;
    #pragma unroll
    for (int m = 0; m < 4; ++m)
      #pragma unroll
      for (int r = 0; r < 4; ++r) {
        int row = m * 16 + hi * 4 + r;
        float sm = 0.f, sq = 0.f;
        #pragma unroll
        for (int w = 0; w < 8; ++w) {
          sm += lnred[row * 16 + w * 2];
          sq += lnred[row * 16 + w * 2 + 1];
        }
        float mu = sm * (1.f / 128.f);
        float var = fmaxf(sq * (1.f / 128.f) - mu * mu, 0.f);
        float rstd = rsqrtf(var + LN_EPS);
        float y = (p0[m][r] - mu) * rstd * g1v + bb1;
        p0[m][r] = y;    // h1res stays in regs
        *reinterpret_cast<ushort*>(M0 + row * 256 + ((chunk ^ (row & 15)) << 4) + sub) = f2b(y);
      }
  }
  __syncthreads();           // h1b visible; lnred done; W1g1 staged

  // ---- ph1: mid = relu(h1b @ W1^T + b1) ----
  f32x4 p1[4][4] = {};
  #pragma unroll
  for (int g = 0; g < 4; ++g) {
    if (g == 0) STG128(w1 + 2 * 16384, 128, 0, (char*)wbuf[1]);   // W1g2
    if (g == 1) STG128(w1 + 3 * 16384, 128, 0, M2);               // W1g3 (g0's M2 dead)
    if (g == 2) STG128(w2, 512, 0,   (char*)wbuf[0]);             // W2k0
    if (g == 3) STG128(w2, 512, 128, (char*)wbuf[1]);             // W2k1
    const char* wB = (g == 0) ? M2
                   : (g == 1) ? (const char*)wbuf[0]
                   : (g == 2) ? (const char*)wbuf[1]
                   : M2;
    #pragma unroll
    for (int kk = 0; kk < 4; ++kk) {
      int c = kk * 4 + hi;
      int wr = wv * 16 + lr;
      bf16x8 aW = *reinterpret_cast<const bf16x8*>(wB + wr * 256 + ((c ^ (wr & 15)) << 4));
      bf16x8 bH[4];
      #pragma unroll
      for (int hj = 0; hj < 4; ++hj) {
        int r = hj * 16 + lr;
        bH[hj] = *reinterpret_cast<const bf16x8*>(M0 + r * 256 + ((c ^ (r & 15)) << 4));
      }
      #pragma unroll
      for (int hj = 0; hj < 4; ++hj)
        p1[g][hj] = __builtin_amdgcn_mfma_f32_16x16x32_bf16(aW, bH[hj], p1[g][hj], 0, 0, 0);
    }
    __syncthreads();
  }

  // ---- write mid [64][512] bf16 (whole 64KB; M0/M1/M2 dead) ----
  #pragma unroll
  for (int g = 0; g < 4; ++g) {
    int mc0 = g * 128 + wv * 16 + hi * 4;
    float4 bv = *reinterpret_cast<const float4*>(b1 + mc0);
    int chunk = mc0 >> 3;
    int sub = (mc0 & 7) * 2;
    #pragma unroll
    for (int hj = 0; hj < 4; ++hj) {
      int orow = hj * 16 + lr;
      ushort4 pk;
      pk.x = f2b(fmaxf(p1[g][hj][0] + bv.x, 0.f));
      pk.y = f2b(fmaxf(p1[g][hj][1] + bv.y, 0.f));
      pk.z = f2b(fmaxf(p1[g][hj][2] + bv.z, 0.f));
      pk.w = f2b(fmaxf(p1[g][hj][3] + bv.w, 0.f));
      char* dstp = (char*)mid + orow * 1024 + (((chunk & 63) ^ (orow & 15)) << 4) + sub;
      *reinterpret_cast<ushort4*>(dstp) = pk;
    }
  }
  __syncthreads();

  // ---- ph2: p2 = mid @ W2^T ----
  f32x4 p2[4] = {};
  #pragma unroll
  for (int g2 = 0; g2 < 4; ++g2) {
    if (g2 == 1) STG128(w2, 512, 256, (char*)wbuf[0]);   // W2k2
    if (g2 == 2) STG128(w2, 512, 384, (char*)wbuf[1]);   // W2k3
    const char* wB = (const char*)wbuf[g2 & 1];
    #pragma unroll
    for (int kk = 0; kk < 4; ++kk) {
      int wr = wv * 16 + lr;
      int cw = kk * 4 + hi;
      bf16x8 bW = *reinterpret_cast<const bf16x8*>(wB + wr * 256 + ((cw ^ (wr & 15)) << 4));
      int cm = g2 * 16 + kk * 4 + hi;
      bf16x8 aM[4];
      #pragma unroll
      for (int m = 0; m < 4; ++m) {
        int r = m * 16 + lr;
        aM[m] = *reinterpret_cast<const bf16x8*>((const char*)mid + r * 1024 + (((cm & 63) ^ (r & 15)) << 4));
      }
      #pragma unroll
      for (int m = 0; m < 4; ++m)
        p2[m] = __builtin_amdgcn_mfma_f32_16x16x32_bf16(aM[m], bW, p2[m], 0, 0, 0);
    }
    __syncthreads();
  }

  // ---- LN2 epilogue: +b2 + h1res(regs), lnred alias wbuf[0] ----
  lnred = reinterpret_cast<float*>(&wbuf[0][0]);
  {
    float bsv = b2[gc];
    #pragma unroll
    for (int m = 0; m < 4; ++m)
      #pragma unroll
      for (int r = 0; r < 4; ++r)
        p2[m][r] += bsv + p0[m][r];
  }
  #pragma unroll
  for (int m = 0; m < 4; ++m)
    #pragma unroll
    for (int r = 0; r < 4; ++r) {
      float sm = p2[m][r];
      float sq = p2[m][r] * p2[m][r];
      #pragma unroll
      for (int msk = 1; msk <= 8; msk <<= 1) {
        sm += __shfl_xor(sm, msk);
        sq += __shfl_xor(sq, msk);
      }
      if (lr == 0) {
        int row = m * 16 + hi * 4 + r;
        lnred[row * 16 + wv * 2]     = sm;
        lnred[row * 16 + wv * 2 + 1] = sq;
      }
    }
  __syncthreads();
  {
    float g2v = ln2g[gc], bb2 = ln2b[gc];
    #pragma unroll
    for (int m = 0; m < 4; ++m)
      #pragma unroll
      for (int r = 0; r < 4; ++r) {
        int row = m * 16 + hi * 4 + r;
        int gr = mbase + row;
        float sm = 0.f, sq = 0.f;
        #pragma unroll
        for (int w = 0; w < 8; ++w) {
          sm += lnred[row * 16 + w * 2];
          sq += lnred[row * 16 + w * 2 + 1];
        }
        float mu = sm * (1.f / 128.f);
        float var = fmaxf(sq * (1.f / 128.f) - mu * mu, 0.f);
        float rstd = rsqrtf(var + LN_EPS);
        if (gr < M)
          outp[(size_t)gr * 128 + gc] = (p2[m][r] - mu) * rstd * g2v + bb2;
      }
  }
}

// ---------------- edge-softmax attention (round-7 proven: fixed-max) ----
__global__ __launch_bounds__(256) void k_attn(
    const ushort* __restrict__ q, const ushort* __restrict__ kv,
    const int* __restrict__ off, const int* __restrict__ csr,
    ushort* __restrict__ sav, int n)
{
  int node = blockIdx.x * 4 + (threadIdx.x >> 6);
  int lane = threadIdx.x & 63;
  if (node >= n) return;
  const int g = lane >> 3, sl = lane & 7;

  const ushort* qr = q + (size_t)node * 128 + sl * 16;
  uint4 qw0 = *reinterpret_cast<const uint4*>(qr);
  uint4 qw1 = *reinterpret_cast<const uint4*>(qr + 8);
  float qv[16];
  unpack8w(qw0, qv); unpack8w(qw1, qv + 8);

  int b = off[node], e = off[node + 1];
  float s = 0.f;
  float a[16] = {};
  int nIt = (e - b + 7) >> 3;
  int idx = b + g;
  int sn = (b < e) ? csr[min(idx, e - 1)] : 0;

  for (int i = 0; i < nIt; ++i) {
    bool act = idx < e;
    const ushort* kr = kv + (size_t)sn * 256 + sl * 16;
    uint4 kw0 = *reinterpret_cast<const uint4*>(kr);
    uint4 kw1 = *reinterpret_cast<const uint4*>(kr + 8);
    uint4 vw0 = *reinterpret_cast<const uint4*>(kr + 128);
    uint4 vw1 = *reinterpret_cast<const uint4*>(kr + 136);
    idx += 8;
    if (i + 1 < nIt) sn = csr[min(idx, e - 1)];

    float kk[16];
    unpack8w(kw0, kk); unpack8w(kw1, kk + 8);
    float p = 0.f;
    #pragma unroll
    for (int j = 0; j < 16; ++j) p = fmaf(qv[j], kk[j], p);
    float u = fminf(fmaxf(p * 0.25f, -CLAMP_V), CLAMP_V);
    float w = __expf(u - CLAMP_V);
    w = act ? w : 0.f;
    s += w;
    float vvv[16];
    unpack8w(vw0, vvv); unpack8w(vw1, vvv + 8);
    #pragma unroll
    for (int j = 0; j < 16; ++j) a[j] = fmaf(w, vvv[j], a[j]);
  }

  #pragma unroll
  for (int msk = 8; msk <= 32; msk <<= 1) {
    s += __shfl_xor(s, msk);
    #pragma unroll
    for (int j = 0; j < 16; ++j) a[j] += __shfl_xor(a[j], msk);
  }

  float inv = (s > 0.f) ? 1.f / s : 0.f;
  if (g == 0) {
    uint w[8];
    #pragma unroll
    for (int j = 0; j < 8; ++j)
      w[j] = (uint)f2b(a[2 * j] * inv) | ((uint)f2b(a[2 * j + 1] * inv) << 16);
    ushort* outp = sav + (size_t)node * 128 + sl * 16;
    uint4 o0 = {w[0], w[1], w[2], w[3]};
    uint4 o1 = {w[4], w[5], w[6], w[7]};
    *reinterpret_cast<uint4*>(outp) = o0;
    *reinterpret_cast<uint4*>(outp + 8) = o1;
  }
}

extern "C" void kernel_launch(void* const* d_in, const int* in_sizes, int n_in,
                              void* d_out, int out_size, void* d_ws, size_t ws_size,
                              hipStream_t stream)
{
  const float* feat = (const float*)d_in[0];
  const int*   src  = (const int*)d_in[1];
  const int*   dst  = (const int*)d_in[2];
  const float* Wq   = (const float*)d_in[3];
  const float* Wk   = (const float*)d_in[4];
  const float* Wv   = (const float*)d_in[5];
  const float* Wo   = (const float*)d_in[6];
  const float* ln1g = (const float*)d_in[7];
  const float* ln1b = (const float*)d_in[8];
  const float* W1   = (const float*)d_in[9];
  const float* b1   = (const float*)d_in[10];
  const float* W2   = (const float*)d_in[11];
  const float* b2   = (const float*)d_in[12];
  const float* ln2g = (const float*)d_in[13];
  const float* ln2b = (const float*)d_in[14];
  float* out = (float*)d_out;

  const int N = in_sizes[0] / DM;
  const int E = in_sizes[1];
  const size_t NB = (size_t)N;

  char* wsb = (char*)d_ws;
  ushort* q_bf    = (ushort*)wsb;
  ushort* kv_bf   = (ushort*)(wsb + NB * 256);
  ushort* sav_bf  = (ushort*)(wsb + NB * 768);
  ushort* feat_bf = (ushort*)(wsb + NB * 1792);
  ushort* wbf     = (ushort*)(wsb + NB * 2048);
  ushort* wqkv_bf = wbf;
  ushort* wo_bf   = wbf + 49152;
  ushort* w1_bf   = wbf + 65536;
  ushort* w2_bf   = wbf + 131072;
  int* ib  = (int*)(wbf + 196608);
  int* deg = ib;
  int* cur = ib + N;
  int* off = ib + 2 * N;
  int* csr = ib + 3 * N + 1;

  hipMemsetAsync(deg, 0, (size_t)N * sizeof(int), stream);

  int nf4 = N * DM / 4;
  int castBlocks = (nf4 + 49152 + 255) / 256;
  int cntBlocks = (E + 255) / 256;
  k_prep<<<castBlocks + cntBlocks, 256, 0, stream>>>(
      feat, Wq, Wk, Wv, Wo, W1, W2, feat_bf, wbf, dst, deg, nf4, castBlocks, E);

  int nbk = (N + SC_EPB - 1) / SC_EPB;
  k_scan<<<nbk, 256, 0, stream>>>(deg, off, cur, N, E);
  k_scatter<<<cntBlocks, 256, 0, stream>>>(src, dst, off, cur, csr, E);

  int nb4 = (N + 3) / 4;
  const int nT = (N + 127) / 128;   // 313

  // qkv: grid (3, nT), split output q_bf | kv_bf
  k_mmT<0><<<dim3(3, nT), 512, 0, stream>>>(feat_bf, wqkv_bf, q_bf, kv_bf, N);

  k_attn<<<nb4, 256, 0, stream>>>(q_bf, kv_bf, off, csr, sav_bf, N);

  // fused: out = LN2(relu(LN1(sav@Wo^T+feat)@W1^T+b1)@W2^T + b2 + h1)
  const int nF = (N + 63) / 64;     // 625
  k_fused<<<nF, 512, 0, stream>>>(
      sav_bf, feat, wo_bf, ln1g, ln1b, w1_bf, b1, w2_bf, b2, ln2g, ln2b, out, N);
}

// Round 14
// 192.235 us; speedup vs baseline: 1.0240x; 1.0240x over previous
//
#include <hip/hip_runtime.h>

#define DM 128
#define DFF 512
#define CLAMP_V 5.0f
#define LN_EPS 1e-5f

typedef __attribute__((ext_vector_type(8))) short bf16x8;
typedef __attribute__((ext_vector_type(4))) float f32x4;
typedef __attribute__((ext_vector_type(2))) float f32x2;

__device__ __forceinline__ float b2f(ushort u) {
  union { uint u; float f; } x; x.u = ((uint)u) << 16; return x.f;
}
__device__ __forceinline__ ushort f2b(float f) {
  union { float f; uint u; } x; x.f = f;
  uint r = x.u + 0x7FFFu + ((x.u >> 16) & 1u);
  return (ushort)(r >> 16);
}
__device__ __forceinline__ f32x2 upk2(uint w) {
  union { uint u; float f; } a, b;
  a.u = w << 16; b.u = w & 0xFFFF0000u;
  f32x2 r; r[0] = a.f; r[1] = b.f; return r;
}

// ---------------- fused prep: feat cast + weight cast + degree count ----------------
__global__ void k_prep(const float* __restrict__ feat,
                       const float* __restrict__ wq, const float* __restrict__ wk,
                       const float* __restrict__ wv, const float* __restrict__ wo,
                       const float* __restrict__ w1, const float* __restrict__ w2,
                       ushort* __restrict__ feat_bf, ushort* __restrict__ wbf,
                       const int* __restrict__ dst, int* __restrict__ deg,
                       int nf4, int castBlocks, int E) {
  if ((int)blockIdx.x >= castBlocks) {
    int e = ((int)blockIdx.x - castBlocks) * 256 + threadIdx.x;
    if (e < E) atomicAdd(&deg[dst[e]], 1);
    return;
  }
  int i = blockIdx.x * 256 + threadIdx.x;
  if (i < nf4) {
    float4 v = *reinterpret_cast<const float4*>(feat + i * 4);
    ushort4 o; o.x = f2b(v.x); o.y = f2b(v.y); o.z = f2b(v.z); o.w = f2b(v.w);
    *reinterpret_cast<ushort4*>(feat_bf + i * 4) = o;
    return;
  }
  int i4 = (i - nf4) * 4;
  if (i4 >= 196608) return;
  const float* s; int o;
  if      (i4 < 16384)  { s = wq; o = i4; }
  else if (i4 < 32768)  { s = wk; o = i4 - 16384; }
  else if (i4 < 49152)  { s = wv; o = i4 - 32768; }
  else if (i4 < 65536)  { s = wo; o = i4 - 49152; }
  else if (i4 < 131072) { s = w1; o = i4 - 65536; }
  else                  { s = w2; o = i4 - 131072; }
  float4 v = *reinterpret_cast<const float4*>(s + o);
  ushort4 u; u.x = f2b(v.x); u.y = f2b(v.y); u.z = f2b(v.z); u.w = f2b(v.w);
  *reinterpret_cast<ushort4*>(wbf + i4) = u;
}

#define SC_EPB 1024

// single-kernel exclusive scan (round-13 proven); also zeroes cur, off[n]=E
__global__ __launch_bounds__(256) void k_scan(const int* __restrict__ deg,
                                              int* __restrict__ off,
                                              int* __restrict__ cur,
                                              int n, int E) {
  __shared__ int sh[256];
  __shared__ int wsum[4];
  const int t = threadIdx.x;
  const int bstart = blockIdx.x * SC_EPB;

  int gs = 0;
  for (int base = t * 4; base < bstart; base += SC_EPB) {
    int4 v = *reinterpret_cast<const int4*>(deg + base);
    gs += v.x + v.y + v.z + v.w;
  }
  #pragma unroll
  for (int m = 1; m < 64; m <<= 1) gs += __shfl_xor(gs, m);
  if ((t & 63) == 0) wsum[t >> 6] = gs;
  __syncthreads();
  int gadd = wsum[0] + wsum[1] + wsum[2] + wsum[3];
  __syncthreads();

  int base = bstart + t * 4;
  int4 v = {0, 0, 0, 0};
  if (base + 3 < n) {
    v = *reinterpret_cast<const int4*>(deg + base);
  } else {
    if (base     < n) v.x = deg[base];
    if (base + 1 < n) v.y = deg[base + 1];
    if (base + 2 < n) v.z = deg[base + 2];
    if (base + 3 < n) v.w = deg[base + 3];
  }
  int s = v.x + v.y + v.z + v.w;
  sh[t] = s;
  __syncthreads();
  #pragma unroll
  for (int d = 1; d < 256; d <<= 1) {
    int x = 0;
    if (t >= d) x = sh[t - d];
    __syncthreads();
    sh[t] += x;
    __syncthreads();
  }
  int ex = sh[t] - s + gadd;
  if (base + 3 < n) {
    int4 o; o.x = ex; o.y = ex + v.x; o.z = ex + v.x + v.y; o.w = ex + v.x + v.y + v.z;
    *reinterpret_cast<int4*>(off + base) = o;
    int4 z = {0, 0, 0, 0};
    *reinterpret_cast<int4*>(cur + base) = z;
  } else {
    if (base     < n) { off[base]     = ex;                    cur[base]     = 0; }
    if (base + 1 < n) { off[base + 1] = ex + v.x;              cur[base + 1] = 0; }
    if (base + 2 < n) { off[base + 2] = ex + v.x + v.y;        cur[base + 2] = 0; }
    if (base + 3 < n) { off[base + 3] = ex + v.x + v.y + v.z;  cur[base + 3] = 0; }
  }
  if (blockIdx.x == 0 && t == 0) off[n] = E;
}

// =====================================================================
// k_sqkv: fused CSR-scatter + qkv GEMM in one dispatch (independent work,
// blockIdx range split). qkv part = round-8 k_mmT with QKV split output.
// =====================================================================
__global__ __launch_bounds__(512, 2) void k_sqkv(
    const ushort* __restrict__ A, const ushort* __restrict__ W,
    ushort* __restrict__ Cb, ushort* __restrict__ Cb2, int M,
    const int* __restrict__ src, const int* __restrict__ dst,
    const int* __restrict__ off, int* __restrict__ cur,
    int* __restrict__ csr, int E, int qkvB)
{
  __shared__ ushort As[128 * 128];
  __shared__ ushort Bs[128 * 128];

  if ((int)blockIdx.x >= qkvB) {
    int e = ((int)blockIdx.x - qkvB) * 512 + threadIdx.x;
    if (e < E) {
      int d = dst[e];
      int p = off[d] + atomicAdd(&cur[d], 1);
      csr[p] = src[e];
    }
    return;
  }

  const int tid = threadIdx.x;
  const int wv = tid >> 6, ln = tid & 63;
  const int bnb = blockIdx.x % 3;
  const int mbase = (blockIdx.x / 3) * 128;
  const int wrow = (wv >> 2) * 64, wcol = (wv & 3) * 32;
  const int o_base = tid * 16;

  #pragma unroll
  for (int is = 0; is < 4; ++is) {
    int o = is * 8192 + o_base;
    int row = o >> 8;
    int c = ((o >> 4) & 15) ^ (row & 15);
    int gr = min(mbase + row, M - 1);
    const ushort* sA = A + (size_t)gr * 128 + c * 8;
    __builtin_amdgcn_global_load_lds(
        (const __attribute__((address_space(1))) void*)sA,
        (__attribute__((address_space(3))) void*)((char*)As + is * 8192 + wv * 1024),
        16, 0, 0);
    const ushort* sB = W + (size_t)(bnb * 128 + row) * 128 + c * 8;
    __builtin_amdgcn_global_load_lds(
        (const __attribute__((address_space(1))) void*)sB,
        (__attribute__((address_space(3))) void*)((char*)Bs + is * 8192 + wv * 1024),
        16, 0, 0);
  }
  __syncthreads();

  f32x4 acc[4][2] = {};
  const char* AsB = (const char*)As;
  const char* BsB = (const char*)Bs;
  #pragma unroll
  for (int kk = 0; kk < 4; ++kk) {
    bf16x8 af[4], bfr[2];
    #pragma unroll
    for (int m = 0; m < 4; ++m) {
      int r = wrow + m * 16 + (ln & 15);
      int c = kk * 4 + (ln >> 4);
      af[m] = *reinterpret_cast<const bf16x8*>(AsB + r * 256 + ((c ^ (r & 15)) << 4));
    }
    #pragma unroll
    for (int n = 0; n < 2; ++n) {
      int r = wcol + n * 16 + (ln & 15);
      int c = kk * 4 + (ln >> 4);
      bfr[n] = *reinterpret_cast<const bf16x8*>(BsB + r * 256 + ((c ^ (r & 15)) << 4));
    }
    #pragma unroll
    for (int m = 0; m < 4; ++m)
      #pragma unroll
      for (int n = 0; n < 2; ++n)
        acc[m][n] = __builtin_amdgcn_mfma_f32_16x16x32_bf16(af[m], bfr[n], acc[m][n], 0, 0, 0);
  }

  #pragma unroll
  for (int m = 0; m < 4; ++m) {
    int gr0 = mbase + wrow + m * 16 + (ln >> 4) * 4;
    #pragma unroll
    for (int n = 0; n < 2; ++n) {
      int gcl = wcol + n * 16 + (ln & 15);
      #pragma unroll
      for (int r = 0; r < 4; ++r) {
        int gr = gr0 + r;
        if (gr >= M) continue;
        float v = acc[m][n][r];
        if (bnb == 0) Cb[(size_t)gr * 128 + gcl] = f2b(v);
        else          Cb2[(size_t)gr * 256 + (bnb - 1) * 128 + gcl] = f2b(v);
      }
    }
  }
}

// =====================================================================
// k_mmT: tile GEMM with LN epilogue (round-12 proven). Used for wo+LN1,
// now writing ONLY bf16 h1b. 512 thr, 8 waves (2x4 of 64x32).
// =====================================================================
template<int FLAGS, bool OUTF, bool OUTB>
__global__ __launch_bounds__(512, 2) void k_mmT(
    const ushort* __restrict__ A, const ushort* __restrict__ W,
    const float* __restrict__ res,
    const float* __restrict__ lng, const float* __restrict__ lnbv,
    float* __restrict__ Cf, ushort* __restrict__ Cb, int M)
{
  __shared__ ushort As[128 * 128];
  __shared__ ushort Bs[128 * 128];
  __shared__ float lnred[1024];

  const int tid = threadIdx.x;
  const int wv = tid >> 6, ln = tid & 63;
  const int mbase = blockIdx.y * 128;
  const int wrow = (wv >> 2) * 64, wcol = (wv & 3) * 32;
  const int o_base = tid * 16;

  #pragma unroll
  for (int is = 0; is < 4; ++is) {
    int o = is * 8192 + o_base;
    int row = o >> 8;
    int c = ((o >> 4) & 15) ^ (row & 15);
    int gr = min(mbase + row, M - 1);
    const ushort* sA = A + (size_t)gr * 128 + c * 8;
    __builtin_amdgcn_global_load_lds(
        (const __attribute__((address_space(1))) void*)sA,
        (__attribute__((address_space(3))) void*)((char*)As + is * 8192 + wv * 1024),
        16, 0, 0);
    const ushort* sB = W + (size_t)row * 128 + c * 8;
    __builtin_amdgcn_global_load_lds(
        (const __attribute__((address_space(1))) void*)sB,
        (__attribute__((address_space(3))) void*)((char*)Bs + is * 8192 + wv * 1024),
        16, 0, 0);
  }
  __syncthreads();

  f32x4 acc[4][2] = {};
  const char* AsB = (const char*)As;
  const char* BsB = (const char*)Bs;
  #pragma unroll
  for (int kk = 0; kk < 4; ++kk) {
    bf16x8 af[4], bfr[2];
    #pragma unroll
    for (int m = 0; m < 4; ++m) {
      int r = wrow + m * 16 + (ln & 15);
      int c = kk * 4 + (ln >> 4);
      af[m] = *reinterpret_cast<const bf16x8*>(AsB + r * 256 + ((c ^ (r & 15)) << 4));
    }
    #pragma unroll
    for (int n = 0; n < 2; ++n) {
      int r = wcol + n * 16 + (ln & 15);
      int c = kk * 4 + (ln >> 4);
      bfr[n] = *reinterpret_cast<const bf16x8*>(BsB + r * 256 + ((c ^ (r & 15)) << 4));
    }
    #pragma unroll
    for (int m = 0; m < 4; ++m)
      #pragma unroll
      for (int n = 0; n < 2; ++n)
        acc[m][n] = __builtin_amdgcn_mfma_f32_16x16x32_bf16(af[m], bfr[n], acc[m][n], 0, 0, 0);
  }

  // fused LN epilogue
  #pragma unroll
  for (int m = 0; m < 4; ++m)
    #pragma unroll
    for (int n = 0; n < 2; ++n) {
      int gc = wcol + n * 16 + (ln & 15);
      #pragma unroll
      for (int r = 0; r < 4; ++r) {
        int gr = mbase + wrow + m * 16 + (ln >> 4) * 4 + r;
        float v = acc[m][n][r];
        if (FLAGS & 4) v += res[(size_t)min(gr, M - 1) * 128 + gc];
        acc[m][n][r] = v;
      }
    }
  #pragma unroll
  for (int m = 0; m < 4; ++m)
    #pragma unroll
    for (int r = 0; r < 4; ++r) {
      float sm = acc[m][0][r] + acc[m][1][r];
      float sq = acc[m][0][r] * acc[m][0][r] + acc[m][1][r] * acc[m][1][r];
      #pragma unroll
      for (int msk = 1; msk <= 8; msk <<= 1) {
        sm += __shfl_xor(sm, msk);
        sq += __shfl_xor(sq, msk);
      }
      if ((ln & 15) == 0) {
        int row = wrow + m * 16 + (ln >> 4) * 4 + r;
        lnred[row * 8 + (wv & 3) * 2]     = sm;
        lnred[row * 8 + (wv & 3) * 2 + 1] = sq;
      }
    }
  __syncthreads();
  #pragma unroll
  for (int m = 0; m < 4; ++m)
    #pragma unroll
    for (int r = 0; r < 4; ++r) {
      int row = wrow + m * 16 + (ln >> 4) * 4 + r;
      int gr = mbase + row;
      float sm = lnred[row * 8] + lnred[row * 8 + 2] + lnred[row * 8 + 4] + lnred[row * 8 + 6];
      float sq = lnred[row * 8 + 1] + lnred[row * 8 + 3] + lnred[row * 8 + 5] + lnred[row * 8 + 7];
      float mu = sm * (1.f / 128.f);
      float var = fmaxf(sq * (1.f / 128.f) - mu * mu, 0.f);
      float rstd = rsqrtf(var + LN_EPS);
      if (gr < M) {
        #pragma unroll
        for (int n = 0; n < 2; ++n) {
          int gc = wcol + n * 16 + (ln & 15);
          float y = (acc[m][n][r] - mu) * rstd * lng[gc] + lnbv[gc];
          if (OUTF) Cf[(size_t)gr * 128 + gc] = y;
          if (OUTB) Cb[(size_t)gr * 128 + gc] = f2b(y);
        }
      }
    }
}

// =====================================================================
// k_ffn (round-12 structure): all-LDS staging, dbuf W tiles; residual h1
// now read from the staged h1b LDS tile (no f32 h1 global roundtrip).
// =====================================================================
__global__ __launch_bounds__(512, 2) void k_ffn(
    const ushort* __restrict__ h1b,
    const ushort* __restrict__ w1, const float* __restrict__ b1,
    const ushort* __restrict__ w2, const float* __restrict__ b2,
    const float* __restrict__ lng, const float* __restrict__ lnbv,
    float* __restrict__ outp, int M)
{
  __shared__ ushort mid[64 * 512];
  __shared__ ushort wbuf[2][128 * 128];

  const int tid = threadIdx.x;
  const int wv = tid >> 6, ln = tid & 63;
  const int lr = ln & 15, hi = ln >> 4;
  const int mbase = blockIdx.x * 64;
  const int gc = wv * 16 + lr;

  auto STG128 = [&](const ushort* srcBase, int srcLd, int colOff, char* dstLds) {
    #pragma unroll
    for (int is = 0; is < 4; ++is) {
      int o = is * 8192 + tid * 16;
      int r = o >> 8;
      int c = ((o >> 4) & 15) ^ (r & 15);
      const ushort* s = srcBase + (size_t)r * srcLd + colOff + c * 8;
      __builtin_amdgcn_global_load_lds(
          (const __attribute__((address_space(1))) void*)s,
          (__attribute__((address_space(3))) void*)(dstLds + is * 8192 + wv * 1024),
          16, 0, 0);
    }
  };

  // prologue: h1b tile -> mid[0:16KB], W1g0 -> wbuf[0]
  #pragma unroll
  for (int is = 0; is < 2; ++is) {
    int o = is * 8192 + tid * 16;
    int r = o >> 8;
    int c = ((o >> 4) & 15) ^ (r & 15);
    int gr = min(mbase + r, M - 1);
    const ushort* s = h1b + (size_t)gr * 128 + c * 8;
    __builtin_amdgcn_global_load_lds(
        (const __attribute__((address_space(1))) void*)s,
        (__attribute__((address_space(3))) void*)((char*)mid + is * 8192 + wv * 1024),
        16, 0, 0);
  }
  STG128(w1, 128, 0, (char*)wbuf[0]);
  __syncthreads();

  // phase 1
  f32x4 p1[4][4] = {};
  const char* hB = (const char*)mid;
  #pragma unroll
  for (int g = 0; g < 4; ++g) {
    const int buf = g & 1;
    if (g < 3) STG128(w1 + (size_t)(g + 1) * 128 * 128, 128, 0, (char*)wbuf[buf ^ 1]);
    else       STG128(w2, 512, 0, (char*)wbuf[buf ^ 1]);
    const char* wB = (const char*)wbuf[buf];
    #pragma unroll
    for (int kk = 0; kk < 4; ++kk) {
      int c = kk * 4 + hi;
      int wr = wv * 16 + lr;
      bf16x8 aW = *reinterpret_cast<const bf16x8*>(wB + wr * 256 + ((c ^ (wr & 15)) << 4));
      bf16x8 bH[4];
      #pragma unroll
      for (int hj = 0; hj < 4; ++hj) {
        int r = hj * 16 + lr;
        bH[hj] = *reinterpret_cast<const bf16x8*>(hB + r * 256 + ((c ^ (r & 15)) << 4));
      }
      #pragma unroll
      for (int hj = 0; hj < 4; ++hj)
        p1[g][hj] = __builtin_amdgcn_mfma_f32_16x16x32_bf16(aW, bH[hj], p1[g][hj], 0, 0, 0);
    }
    __syncthreads();
  }

  // residual h1 from staged LDS tile (before overwrite)
  float h1res[4][4];
  {
    int chunk = gc >> 3;
    int sub = (gc & 7) * 2;
    #pragma unroll
    for (int m = 0; m < 4; ++m)
      #pragma unroll
      for (int r = 0; r < 4; ++r) {
        int row = m * 16 + hi * 4 + r;
        h1res[m][r] = b2f(*reinterpret_cast<const ushort*>(
            (const char*)mid + row * 256 + ((chunk ^ (row & 15)) << 4) + sub));
      }
  }
  __syncthreads();

  // write mid [64][512] bf16
  #pragma unroll
  for (int g = 0; g < 4; ++g) {
    int mc0 = g * 128 + wv * 16 + hi * 4;
    float4 bv = *reinterpret_cast<const float4*>(b1 + mc0);
    int chunk = mc0 >> 3;
    int sub = (mc0 & 7) * 2;
    #pragma unroll
    for (int hj = 0; hj < 4; ++hj) {
      int orow = hj * 16 + lr;
      ushort4 pk;
      pk.x = f2b(fmaxf(p1[g][hj][0] + bv.x, 0.f));
      pk.y = f2b(fmaxf(p1[g][hj][1] + bv.y, 0.f));
      pk.z = f2b(fmaxf(p1[g][hj][2] + bv.z, 0.f));
      pk.w = f2b(fmaxf(p1[g][hj][3] + bv.w, 0.f));
      char* dstp = (char*)mid + orow * 1024 + (((chunk & 63) ^ (orow & 15)) << 4) + sub;
      *reinterpret_cast<ushort4*>(dstp) = pk;
    }
  }
  __syncthreads();

  // phase 2
  f32x4 p2[4] = {};
  #pragma unroll
  for (int g2 = 0; g2 < 4; ++g2) {
    const int buf = g2 & 1;
    if (g2 < 3) STG128(w2, 512, (g2 + 1) * 128, (char*)wbuf[buf ^ 1]);
    const char* wB = (const char*)wbuf[buf];
    #pragma unroll
    for (int kk = 0; kk < 4; ++kk) {
      int wr = wv * 16 + lr;
      int cw = kk * 4 + hi;
      bf16x8 bW = *reinterpret_cast<const bf16x8*>(wB + wr * 256 + ((cw ^ (wr & 15)) << 4));
      int cm = g2 * 16 + kk * 4 + hi;
      bf16x8 aM[4];
      #pragma unroll
      for (int m = 0; m < 4; ++m) {
        int r = m * 16 + lr;
        aM[m] = *reinterpret_cast<const bf16x8*>((const char*)mid + r * 1024 + (((cm & 63) ^ (r & 15)) << 4));
      }
      #pragma unroll
      for (int m = 0; m < 4; ++m)
        p2[m] = __builtin_amdgcn_mfma_f32_16x16x32_bf16(aM[m], bW, p2[m], 0, 0, 0);
    }
    __syncthreads();
  }

  // LN2 epilogue (+b2 + h1res)
  float* lnred = reinterpret_cast<float*>(&wbuf[0][0]);
  {
    float bsv = b2[gc];
    #pragma unroll
    for (int m = 0; m < 4; ++m)
      #pragma unroll
      for (int r = 0; r < 4; ++r)
        p2[m][r] += bsv + h1res[m][r];
  }
  #pragma unroll
  for (int m = 0; m < 4; ++m)
    #pragma unroll
    for (int r = 0; r < 4; ++r) {
      float sm = p2[m][r];
      float sq = p2[m][r] * p2[m][r];
      #pragma unroll
      for (int msk = 1; msk <= 8; msk <<= 1) {
        sm += __shfl_xor(sm, msk);
        sq += __shfl_xor(sq, msk);
      }
      if (lr == 0) {
        int row = m * 16 + hi * 4 + r;
        lnred[row * 16 + wv * 2]     = sm;
        lnred[row * 16 + wv * 2 + 1] = sq;
      }
    }
  __syncthreads();
  {
    float g2v = lng[gc], bb2 = lnbv[gc];
    #pragma unroll
    for (int m = 0; m < 4; ++m)
      #pragma unroll
      for (int r = 0; r < 4; ++r) {
        int row = m * 16 + hi * 4 + r;
        int gr = mbase + row;
        float sm = 0.f, sq = 0.f;
        #pragma unroll
        for (int w = 0; w < 8; ++w) {
          sm += lnred[row * 16 + w * 2];
          sq += lnred[row * 16 + w * 2 + 1];
        }
        float mu = sm * (1.f / 128.f);
        float var = fmaxf(sq * (1.f / 128.f) - mu * mu, 0.f);
        float rstd = rsqrtf(var + LN_EPS);
        if (gr < M)
          outp[(size_t)gr * 128 + gc] = (p2[m][r] - mu) * rstd * g2v + bb2;
      }
  }
}

// ---------------- edge-softmax attention: fixed-max + packed-f32 math ----
__global__ __launch_bounds__(256) void k_attn(
    const ushort* __restrict__ q, const ushort* __restrict__ kv,
    const int* __restrict__ off, const int* __restrict__ csr,
    ushort* __restrict__ sav, int n)
{
  int node = blockIdx.x * 4 + (threadIdx.x >> 6);
  int lane = threadIdx.x & 63;
  if (node >= n) return;
  const int g = lane >> 3, sl = lane & 7;

  const ushort* qr = q + (size_t)node * 128 + sl * 16;
  uint4 qw0 = *reinterpret_cast<const uint4*>(qr);
  uint4 qw1 = *reinterpret_cast<const uint4*>(qr + 8);
  f32x2 qv[8];
  qv[0] = upk2(qw0.x); qv[1] = upk2(qw0.y); qv[2] = upk2(qw0.z); qv[3] = upk2(qw0.w);
  qv[4] = upk2(qw1.x); qv[5] = upk2(qw1.y); qv[6] = upk2(qw1.z); qv[7] = upk2(qw1.w);

  int b = off[node], e = off[node + 1];
  float s = 0.f;
  f32x2 a2[8] = {};
  int nIt = (e - b + 7) >> 3;
  int idx = b + g;
  int sn = (b < e) ? csr[min(idx, e - 1)] : 0;

  for (int i = 0; i < nIt; ++i) {
    bool act = idx < e;
    const ushort* kr = kv + (size_t)sn * 256 + sl * 16;
    uint4 kw0 = *reinterpret_cast<const uint4*>(kr);
    uint4 kw1 = *reinterpret_cast<const uint4*>(kr + 8);
    uint4 vw0 = *reinterpret_cast<const uint4*>(kr + 128);
    uint4 vw1 = *reinterpret_cast<const uint4*>(kr + 136);
    idx += 8;
    if (i + 1 < nIt) sn = csr[min(idx, e - 1)];

    f32x2 acc = qv[0] * upk2(kw0.x);
    acc += qv[1] * upk2(kw0.y);
    acc += qv[2] * upk2(kw0.z);
    acc += qv[3] * upk2(kw0.w);
    acc += qv[4] * upk2(kw1.x);
    acc += qv[5] * upk2(kw1.y);
    acc += qv[6] * upk2(kw1.z);
    acc += qv[7] * upk2(kw1.w);
    float p = acc[0] + acc[1];
    float u = fminf(fmaxf(p * 0.25f, -CLAMP_V), CLAMP_V);
    float w = __expf(u - CLAMP_V);
    w = act ? w : 0.f;
    s += w;
    f32x2 w2; w2[0] = w; w2[1] = w;
    a2[0] += w2 * upk2(vw0.x);
    a2[1] += w2 * upk2(vw0.y);
    a2[2] += w2 * upk2(vw0.z);
    a2[3] += w2 * upk2(vw0.w);
    a2[4] += w2 * upk2(vw1.x);
    a2[5] += w2 * upk2(vw1.y);
    a2[6] += w2 * upk2(vw1.z);
    a2[7] += w2 * upk2(vw1.w);
  }

  #pragma unroll
  for (int msk = 8; msk <= 32; msk <<= 1) {
    s += __shfl_xor(s, msk);
    #pragma unroll
    for (int j = 0; j < 8; ++j) {
      a2[j][0] += __shfl_xor(a2[j][0], msk);
      a2[j][1] += __shfl_xor(a2[j][1], msk);
    }
  }

  float inv = (s > 0.f) ? 1.f / s : 0.f;
  if (g == 0) {
    uint w[8];
    #pragma unroll
    for (int j = 0; j < 8; ++j)
      w[j] = (uint)f2b(a2[j][0] * inv) | ((uint)f2b(a2[j][1] * inv) << 16);
    ushort* outp = sav + (size_t)node * 128 + sl * 16;
    uint4 o0 = {w[0], w[1], w[2], w[3]};
    uint4 o1 = {w[4], w[5], w[6], w[7]};
    *reinterpret_cast<uint4*>(outp) = o0;
    *reinterpret_cast<uint4*>(outp + 8) = o1;
  }
}

extern "C" void kernel_launch(void* const* d_in, const int* in_sizes, int n_in,
                              void* d_out, int out_size, void* d_ws, size_t ws_size,
                              hipStream_t stream)
{
  const float* feat = (const float*)d_in[0];
  const int*   src  = (const int*)d_in[1];
  const int*   dst  = (const int*)d_in[2];
  const float* Wq   = (const float*)d_in[3];
  const float* Wk   = (const float*)d_in[4];
  const float* Wv   = (const float*)d_in[5];
  const float* Wo   = (const float*)d_in[6];
  const float* ln1g = (const float*)d_in[7];
  const float* ln1b = (const float*)d_in[8];
  const float* W1   = (const float*)d_in[9];
  const float* b1   = (const float*)d_in[10];
  const float* W2   = (const float*)d_in[11];
  const float* b2   = (const float*)d_in[12];
  const float* ln2g = (const float*)d_in[13];
  const float* ln2b = (const float*)d_in[14];
  float* out = (float*)d_out;

  const int N = in_sizes[0] / DM;
  const int E = in_sizes[1];
  const size_t NB = (size_t)N;

  char* wsb = (char*)d_ws;
  ushort* q_bf    = (ushort*)wsb;
  ushort* kv_bf   = (ushort*)(wsb + NB * 256);
  ushort* sav_bf  = (ushort*)(wsb + NB * 768);
  ushort* h1b     = (ushort*)(wsb + NB * 1536);
  ushort* feat_bf = (ushort*)(wsb + NB * 1792);
  ushort* wbf     = (ushort*)(wsb + NB * 2048);
  ushort* wqkv_bf = wbf;
  ushort* wo_bf   = wbf + 49152;
  ushort* w1_bf   = wbf + 65536;
  ushort* w2_bf   = wbf + 131072;
  int* ib  = (int*)(wbf + 196608);
  int* deg = ib;
  int* cur = ib + N;
  int* off = ib + 2 * N;
  int* csr = ib + 3 * N + 1;

  hipMemsetAsync(deg, 0, (size_t)N * sizeof(int), stream);

  int nf4 = N * DM / 4;
  int castBlocks = (nf4 + 49152 + 255) / 256;
  int cntBlocks = (E + 255) / 256;
  k_prep<<<castBlocks + cntBlocks, 256, 0, stream>>>(
      feat, Wq, Wk, Wv, Wo, W1, W2, feat_bf, wbf, dst, deg, nf4, castBlocks, E);

  int nbk = (N + SC_EPB - 1) / SC_EPB;
  k_scan<<<nbk, 256, 0, stream>>>(deg, off, cur, N, E);

  const int nT = (N + 127) / 128;   // 313
  int qkvB = 3 * nT;
  int scB = (E + 511) / 512;
  k_sqkv<<<qkvB + scB, 512, 0, stream>>>(
      feat_bf, wqkv_bf, q_bf, kv_bf, N, src, dst, off, cur, csr, E, qkvB);

  int nb4 = (N + 3) / 4;
  k_attn<<<nb4, 256, 0, stream>>>(q_bf, kv_bf, off, csr, sav_bf, N);

  // h1b = LN1(sav @ Wo^T + feat)  (bf16 only; no f32 h1 roundtrip)
  k_mmT<4 | 8, false, true><<<dim3(1, nT), 512, 0, stream>>>(
      sav_bf, wo_bf, feat, ln1g, ln1b, nullptr, h1b, N);

  // fused FFN: out = LN2(relu(h1b@W1^T+b1)@W2^T + b2 + h1b_res)
  const int nF = (N + 63) / 64;     // 625
  k_ffn<<<nF, 512, 0, stream>>>(
      h1b, w1_bf, b1, w2_bf, b2, ln2g, ln2b, out, N);
}

// Round 16
// 190.649 us; speedup vs baseline: 1.0325x; 1.0083x over previous
//
#include <hip/hip_runtime.h>

#define DM 128
#define DFF 512
#define CLAMP_V 5.0f
#define LN_EPS 1e-5f

typedef __attribute__((ext_vector_type(8))) short bf16x8;
typedef __attribute__((ext_vector_type(4))) float f32x4;
typedef __attribute__((ext_vector_type(2))) float f32x2;

__device__ __forceinline__ float b2f(ushort u) {
  union { uint u; float f; } x; x.u = ((uint)u) << 16; return x.f;
}
__device__ __forceinline__ ushort f2b(float f) {
  union { float f; uint u; } x; x.f = f;
  uint r = x.u + 0x7FFFu + ((x.u >> 16) & 1u);
  return (ushort)(r >> 16);
}
__device__ __forceinline__ f32x2 upk2(uint w) {
  union { uint u; float f; } a, b;
  a.u = w << 16; b.u = w & 0xFFFF0000u;
  f32x2 r; r[0] = a.f; r[1] = b.f; return r;
}

// ---------------- fused prep: feat cast + weight cast + degree count ----------------
__global__ void k_prep(const float* __restrict__ feat,
                       const float* __restrict__ wq, const float* __restrict__ wk,
                       const float* __restrict__ wv, const float* __restrict__ wo,
                       const float* __restrict__ w1, const float* __restrict__ w2,
                       ushort* __restrict__ feat_bf, ushort* __restrict__ wbf,
                       const int* __restrict__ dst, int* __restrict__ deg,
                       int nf4, int castBlocks, int E) {
  if ((int)blockIdx.x >= castBlocks) {
    int e = ((int)blockIdx.x - castBlocks) * 256 + threadIdx.x;
    if (e < E) atomicAdd(&deg[dst[e]], 1);
    return;
  }
  int i = blockIdx.x * 256 + threadIdx.x;
  if (i < nf4) {
    float4 v = *reinterpret_cast<const float4*>(feat + i * 4);
    ushort4 o; o.x = f2b(v.x); o.y = f2b(v.y); o.z = f2b(v.z); o.w = f2b(v.w);
    *reinterpret_cast<ushort4*>(feat_bf + i * 4) = o;
    return;
  }
  int i4 = (i - nf4) * 4;
  if (i4 >= 196608) return;
  const float* s; int o;
  if      (i4 < 16384)  { s = wq; o = i4; }
  else if (i4 < 32768)  { s = wk; o = i4 - 16384; }
  else if (i4 < 49152)  { s = wv; o = i4 - 32768; }
  else if (i4 < 65536)  { s = wo; o = i4 - 49152; }
  else if (i4 < 131072) { s = w1; o = i4 - 65536; }
  else                  { s = w2; o = i4 - 131072; }
  float4 v = *reinterpret_cast<const float4*>(s + o);
  ushort4 u; u.x = f2b(v.x); u.y = f2b(v.y); u.z = f2b(v.z); u.w = f2b(v.w);
  *reinterpret_cast<ushort4*>(wbf + i4) = u;
}

#define SC_EPB 1024

// single-kernel exclusive scan; also zeroes cur, writes off[n]=E
__global__ __launch_bounds__(256) void k_scan(const int* __restrict__ deg,
                                              int* __restrict__ off,
                                              int* __restrict__ cur,
                                              int n, int E) {
  __shared__ int sh[256];
  __shared__ int wsum[4];
  const int t = threadIdx.x;
  const int bstart = blockIdx.x * SC_EPB;

  int gs = 0;
  for (int base = t * 4; base < bstart; base += SC_EPB) {
    int4 v = *reinterpret_cast<const int4*>(deg + base);
    gs += v.x + v.y + v.z + v.w;
  }
  #pragma unroll
  for (int m = 1; m < 64; m <<= 1) gs += __shfl_xor(gs, m);
  if ((t & 63) == 0) wsum[t >> 6] = gs;
  __syncthreads();
  int gadd = wsum[0] + wsum[1] + wsum[2] + wsum[3];
  __syncthreads();

  int base = bstart + t * 4;
  int4 v = {0, 0, 0, 0};
  if (base + 3 < n) {
    v = *reinterpret_cast<const int4*>(deg + base);
  } else {
    if (base     < n) v.x = deg[base];
    if (base + 1 < n) v.y = deg[base + 1];
    if (base + 2 < n) v.z = deg[base + 2];
    if (base + 3 < n) v.w = deg[base + 3];
  }
  int s = v.x + v.y + v.z + v.w;
  sh[t] = s;
  __syncthreads();
  #pragma unroll
  for (int d = 1; d < 256; d <<= 1) {
    int x = 0;
    if (t >= d) x = sh[t - d];
    __syncthreads();
    sh[t] += x;
    __syncthreads();
  }
  int ex = sh[t] - s + gadd;
  if (base + 3 < n) {
    int4 o; o.x = ex; o.y = ex + v.x; o.z = ex + v.x + v.y; o.w = ex + v.x + v.y + v.z;
    *reinterpret_cast<int4*>(off + base) = o;
    int4 z = {0, 0, 0, 0};
    *reinterpret_cast<int4*>(cur + base) = z;
  } else {
    if (base     < n) { off[base]     = ex;                    cur[base]     = 0; }
    if (base + 1 < n) { off[base + 1] = ex + v.x;              cur[base + 1] = 0; }
    if (base + 2 < n) { off[base + 2] = ex + v.x + v.y;        cur[base + 2] = 0; }
    if (base + 3 < n) { off[base + 3] = ex + v.x + v.y + v.z;  cur[base + 3] = 0; }
  }
  if (blockIdx.x == 0 && t == 0) off[n] = E;
}

// standalone scatter (0 LDS, full occupancy)
__global__ void k_scatter(const int* __restrict__ src, const int* __restrict__ dst,
                          const int* __restrict__ off, int* __restrict__ cur,
                          int* __restrict__ csr, int E) {
  int e = blockIdx.x * blockDim.x + threadIdx.x;
  if (e < E) {
    int d = dst[e];
    int p = off[d] + atomicAdd(&cur[d], 1);
    csr[p] = src[e];
  }
}

// =====================================================================
// k_qkv: one-tile-per-block GEMM, QKV split output. 512 thr, 2 blk/CU.
// =====================================================================
__global__ __launch_bounds__(512, 2) void k_qkv(
    const ushort* __restrict__ A, const ushort* __restrict__ W,
    ushort* __restrict__ Cb, ushort* __restrict__ Cb2, int M)
{
  __shared__ ushort As[128 * 128];
  __shared__ ushort Bs[128 * 128];

  const int tid = threadIdx.x;
  const int wv = tid >> 6, ln = tid & 63;
  const int bnb = blockIdx.x;
  const int mbase = blockIdx.y * 128;
  const int wrow = (wv >> 2) * 64, wcol = (wv & 3) * 32;
  const int o_base = tid * 16;

  #pragma unroll
  for (int is = 0; is < 4; ++is) {
    int o = is * 8192 + o_base;
    int row = o >> 8;
    int c = ((o >> 4) & 15) ^ (row & 15);
    int gr = min(mbase + row, M - 1);
    const ushort* sA = A + (size_t)gr * 128 + c * 8;
    __builtin_amdgcn_global_load_lds(
        (const __attribute__((address_space(1))) void*)sA,
        (__attribute__((address_space(3))) void*)((char*)As + is * 8192 + wv * 1024),
        16, 0, 0);
    const ushort* sB = W + (size_t)(bnb * 128 + row) * 128 + c * 8;
    __builtin_amdgcn_global_load_lds(
        (const __attribute__((address_space(1))) void*)sB,
        (__attribute__((address_space(3))) void*)((char*)Bs + is * 8192 + wv * 1024),
        16, 0, 0);
  }
  __syncthreads();

  f32x4 acc[4][2] = {};
  const char* AsB = (const char*)As;
  const char* BsB = (const char*)Bs;
  #pragma unroll
  for (int kk = 0; kk < 4; ++kk) {
    bf16x8 af[4], bfr[2];
    #pragma unroll
    for (int m = 0; m < 4; ++m) {
      int r = wrow + m * 16 + (ln & 15);
      int c = kk * 4 + (ln >> 4);
      af[m] = *reinterpret_cast<const bf16x8*>(AsB + r * 256 + ((c ^ (r & 15)) << 4));
    }
    #pragma unroll
    for (int n = 0; n < 2; ++n) {
      int r = wcol + n * 16 + (ln & 15);
      int c = kk * 4 + (ln >> 4);
      bfr[n] = *reinterpret_cast<const bf16x8*>(BsB + r * 256 + ((c ^ (r & 15)) << 4));
    }
    #pragma unroll
    for (int m = 0; m < 4; ++m)
      #pragma unroll
      for (int n = 0; n < 2; ++n)
        acc[m][n] = __builtin_amdgcn_mfma_f32_16x16x32_bf16(af[m], bfr[n], acc[m][n], 0, 0, 0);
  }

  #pragma unroll
  for (int m = 0; m < 4; ++m) {
    int gr0 = mbase + wrow + m * 16 + (ln >> 4) * 4;
    #pragma unroll
    for (int n = 0; n < 2; ++n) {
      int gcl = wcol + n * 16 + (ln & 15);
      #pragma unroll
      for (int r = 0; r < 4; ++r) {
        int gr = gr0 + r;
        if (gr >= M) continue;
        float v = acc[m][n][r];
        if (bnb == 0) Cb[(size_t)gr * 128 + gcl] = f2b(v);
        else          Cb2[(size_t)gr * 256 + (bnb - 1) * 128 + gcl] = f2b(v);
      }
    }
  }
}

// =====================================================================
// k_mmT: wo-GEMM + LN1 -> bf16 h1b only (round-14 proven).
// =====================================================================
__global__ __launch_bounds__(512, 2) void k_mmT(
    const ushort* __restrict__ A, const ushort* __restrict__ W,
    const float* __restrict__ res,
    const float* __restrict__ lng, const float* __restrict__ lnbv,
    ushort* __restrict__ Cb, int M)
{
  __shared__ ushort As[128 * 128];
  __shared__ ushort Bs[128 * 128];
  __shared__ float lnred[1024];

  const int tid = threadIdx.x;
  const int wv = tid >> 6, ln = tid & 63;
  const int mbase = blockIdx.y * 128;
  const int wrow = (wv >> 2) * 64, wcol = (wv & 3) * 32;
  const int o_base = tid * 16;

  #pragma unroll
  for (int is = 0; is < 4; ++is) {
    int o = is * 8192 + o_base;
    int row = o >> 8;
    int c = ((o >> 4) & 15) ^ (row & 15);
    int gr = min(mbase + row, M - 1);
    const ushort* sA = A + (size_t)gr * 128 + c * 8;
    __builtin_amdgcn_global_load_lds(
        (const __attribute__((address_space(1))) void*)sA,
        (__attribute__((address_space(3))) void*)((char*)As + is * 8192 + wv * 1024),
        16, 0, 0);
    const ushort* sB = W + (size_t)row * 128 + c * 8;
    __builtin_amdgcn_global_load_lds(
        (const __attribute__((address_space(1))) void*)sB,
        (__attribute__((address_space(3))) void*)((char*)Bs + is * 8192 + wv * 1024),
        16, 0, 0);
  }
  __syncthreads();

  f32x4 acc[4][2] = {};
  const char* AsB = (const char*)As;
  const char* BsB = (const char*)Bs;
  #pragma unroll
  for (int kk = 0; kk < 4; ++kk) {
    bf16x8 af[4], bfr[2];
    #pragma unroll
    for (int m = 0; m < 4; ++m) {
      int r = wrow + m * 16 + (ln & 15);
      int c = kk * 4 + (ln >> 4);
      af[m] = *reinterpret_cast<const bf16x8*>(AsB + r * 256 + ((c ^ (r & 15)) << 4));
    }
    #pragma unroll
    for (int n = 0; n < 2; ++n) {
      int r = wcol + n * 16 + (ln & 15);
      int c = kk * 4 + (ln >> 4);
      bfr[n] = *reinterpret_cast<const bf16x8*>(BsB + r * 256 + ((c ^ (r & 15)) << 4));
    }
    #pragma unroll
    for (int m = 0; m < 4; ++m)
      #pragma unroll
      for (int n = 0; n < 2; ++n)
        acc[m][n] = __builtin_amdgcn_mfma_f32_16x16x32_bf16(af[m], bfr[n], acc[m][n], 0, 0, 0);
  }

  #pragma unroll
  for (int m = 0; m < 4; ++m)
    #pragma unroll
    for (int n = 0; n < 2; ++n) {
      int gc = wcol + n * 16 + (ln & 15);
      #pragma unroll
      for (int r = 0; r < 4; ++r) {
        int gr = mbase + wrow + m * 16 + (ln >> 4) * 4 + r;
        acc[m][n][r] += res[(size_t)min(gr, M - 1) * 128 + gc];
      }
    }
  #pragma unroll
  for (int m = 0; m < 4; ++m)
    #pragma unroll
    for (int r = 0; r < 4; ++r) {
      float sm = acc[m][0][r] + acc[m][1][r];
      float sq = acc[m][0][r] * acc[m][0][r] + acc[m][1][r] * acc[m][1][r];
      #pragma unroll
      for (int msk = 1; msk <= 8; msk <<= 1) {
        sm += __shfl_xor(sm, msk);
        sq += __shfl_xor(sq, msk);
      }
      if ((ln & 15) == 0) {
        int row = wrow + m * 16 + (ln >> 4) * 4 + r;
        lnred[row * 8 + (wv & 3) * 2]     = sm;
        lnred[row * 8 + (wv & 3) * 2 + 1] = sq;
      }
    }
  __syncthreads();
  #pragma unroll
  for (int m = 0; m < 4; ++m)
    #pragma unroll
    for (int r = 0; r < 4; ++r) {
      int row = wrow + m * 16 + (ln >> 4) * 4 + r;
      int gr = mbase + row;
      float sm = lnred[row * 8] + lnred[row * 8 + 2] + lnred[row * 8 + 4] + lnred[row * 8 + 6];
      float sq = lnred[row * 8 + 1] + lnred[row * 8 + 3] + lnred[row * 8 + 5] + lnred[row * 8 + 7];
      float mu = sm * (1.f / 128.f);
      float var = fmaxf(sq * (1.f / 128.f) - mu * mu, 0.f);
      float rstd = rsqrtf(var + LN_EPS);
      if (gr < M) {
        #pragma unroll
        for (int n = 0; n < 2; ++n) {
          int gc = wcol + n * 16 + (ln & 15);
          float y = (acc[m][n][r] - mu) * rstd * lng[gc] + lnbv[gc];
          Cb[(size_t)gr * 128 + gc] = f2b(y);
        }
      }
    }
}

// =====================================================================
// k_ffn: 32 rows/block, 66KB LDS -> 2 blocks/CU. W1/W2 staged as
// [128][64] k-half tiles, double-buffered (FIXED parity: stage kt+1
// into wbuf[(kt+1)&1], read wbuf[kt&1]). Residual from staged h1b.
// =====================================================================
__global__ __launch_bounds__(512, 4) void k_ffn(
    const ushort* __restrict__ h1b,
    const ushort* __restrict__ w1, const float* __restrict__ b1,
    const ushort* __restrict__ w2, const float* __restrict__ b2,
    const float* __restrict__ lng, const float* __restrict__ lnbv,
    float* __restrict__ outp, int M)
{
  __shared__ ushort mid[32 * 512];        // 32KB; h1b tile lives in first 8KB initially
  __shared__ ushort wbuf[2][128 * 64];    // 2 x 16KB, [128 rows][128B]
  __shared__ float lnred[32 * 16];        // 2KB

  const int tid = threadIdx.x;
  const int wv = tid >> 6, ln = tid & 63;
  const int lr = ln & 15, hi = ln >> 4;
  const int mbase = blockIdx.x * 32;
  const int gc = wv * 16 + lr;

  // stage a [128][64] bf16 tile (16KB, 128B rows, 8-chunk XOR swizzle)
  auto STG64 = [&](const ushort* srcBase, int srcLd, int colOff, char* dstLds) {
    #pragma unroll
    for (int is = 0; is < 2; ++is) {
      int o = is * 8192 + tid * 16;
      int r = o >> 7;
      int c = ((o >> 4) & 7) ^ (r & 7);
      const ushort* s = srcBase + (size_t)r * srcLd + colOff + c * 8;
      __builtin_amdgcn_global_load_lds(
          (const __attribute__((address_space(1))) void*)s,
          (__attribute__((address_space(3))) void*)(dstLds + is * 8192 + wv * 1024),
          16, 0, 0);
    }
  };

  // prologue: h1b tile [32][128] -> mid[0:8KB] (256B rows); W1 tile0 -> wbuf[0]
  {
    int o = tid * 16;
    int r = o >> 8;
    int c = ((o >> 4) & 15) ^ (r & 15);
    int gr = min(mbase + r, M - 1);
    const ushort* s = h1b + (size_t)gr * 128 + c * 8;
    __builtin_amdgcn_global_load_lds(
        (const __attribute__((address_space(1))) void*)s,
        (__attribute__((address_space(3))) void*)((char*)mid + wv * 1024),
        16, 0, 0);
  }
  STG64(w1, 128, 0, (char*)wbuf[0]);
  __syncthreads();

  // ---- phase 1: mid = relu(h1b @ W1^T + b1); 8 steps (4 row-groups x 2 k-halves)
  // step s: read wbuf[s&1]; stage step s+1 into wbuf[(s+1)&1].
  f32x4 p1[4][2] = {};
  const char* hB = (const char*)mid;
  #pragma unroll
  for (int g = 0; g < 4; ++g) {
    #pragma unroll
    for (int kh = 0; kh < 2; ++kh) {
      const int step = g * 2 + kh;
      if (step < 7) {
        int ns = step + 1;
        STG64(w1 + (size_t)(ns >> 1) * 128 * 128, 128, (ns & 1) * 64, (char*)wbuf[ns & 1]);
      } else {
        STG64(w2, 512, 0, (char*)wbuf[0]);   // W2 k-tile 0 -> wbuf[0] (= wbuf[0&1] for ph2 kt=0)
      }
      const char* wB = (const char*)wbuf[step & 1];
      #pragma unroll
      for (int kk = 0; kk < 2; ++kk) {
        int ct = kk * 4 + hi;                 // chunk within [128][64] tile
        int cg = kh * 8 + ct;                 // global k-chunk (h1b row has 16)
        int wr = wv * 16 + lr;
        bf16x8 aW = *reinterpret_cast<const bf16x8*>(wB + wr * 128 + ((ct ^ (wr & 7)) << 4));
        bf16x8 bH[2];
        #pragma unroll
        for (int hj = 0; hj < 2; ++hj) {
          int r = hj * 16 + lr;
          bH[hj] = *reinterpret_cast<const bf16x8*>(hB + r * 256 + ((cg ^ (r & 15)) << 4));
        }
        #pragma unroll
        for (int hj = 0; hj < 2; ++hj)
          p1[g][hj] = __builtin_amdgcn_mfma_f32_16x16x32_bf16(aW, bH[hj], p1[g][hj], 0, 0, 0);
      }
      __syncthreads();
    }
  }

  // residual h1 from staged tile (before overwrite)
  float h1res[2][4];
  {
    int chunk = gc >> 3;
    int sub = (gc & 7) * 2;
    #pragma unroll
    for (int m = 0; m < 2; ++m)
      #pragma unroll
      for (int r = 0; r < 4; ++r) {
        int row = m * 16 + hi * 4 + r;
        h1res[m][r] = b2f(*reinterpret_cast<const ushort*>(
            (const char*)mid + row * 256 + ((chunk ^ (row & 15)) << 4) + sub));
      }
  }
  __syncthreads();

  // write mid [32][512] bf16, 1024B rows, 64-chunk XOR swizzle
  #pragma unroll
  for (int g = 0; g < 4; ++g) {
    int mc0 = g * 128 + wv * 16 + hi * 4;
    float4 bv = *reinterpret_cast<const float4*>(b1 + mc0);
    int chunk = mc0 >> 3;
    int sub = (mc0 & 7) * 2;
    #pragma unroll
    for (int hj = 0; hj < 2; ++hj) {
      int orow = hj * 16 + lr;
      ushort4 pk;
      pk.x = f2b(fmaxf(p1[g][hj][0] + bv.x, 0.f));
      pk.y = f2b(fmaxf(p1[g][hj][1] + bv.y, 0.f));
      pk.z = f2b(fmaxf(p1[g][hj][2] + bv.z, 0.f));
      pk.w = f2b(fmaxf(p1[g][hj][3] + bv.w, 0.f));
      char* dstp = (char*)mid + orow * 1024 + (((chunk & 63) ^ (orow & 15)) << 4) + sub;
      *reinterpret_cast<ushort4*>(dstp) = pk;
    }
  }
  __syncthreads();

  // ---- phase 2: p2 = mid @ W2^T; 8 k-tiles of [128][64].
  // tile kt lives in wbuf[kt&1]; stage kt+1 into wbuf[(kt+1)&1].
  f32x4 p2[2] = {};
  #pragma unroll
  for (int kt = 0; kt < 8; ++kt) {
    if (kt < 7) STG64(w2, 512, (kt + 1) * 64, (char*)wbuf[(kt + 1) & 1]);
    const char* wB = (const char*)wbuf[kt & 1];
    #pragma unroll
    for (int kk = 0; kk < 2; ++kk) {
      int ct = kk * 4 + hi;
      int cm = kt * 8 + ct;                  // global mid chunk (0..63)
      int wr = wv * 16 + lr;
      bf16x8 bW = *reinterpret_cast<const bf16x8*>(wB + wr * 128 + ((ct ^ (wr & 7)) << 4));
      bf16x8 aM[2];
      #pragma unroll
      for (int m = 0; m < 2; ++m) {
        int r = m * 16 + lr;
        aM[m] = *reinterpret_cast<const bf16x8*>((const char*)mid + r * 1024 + (((cm & 63) ^ (r & 15)) << 4));
      }
      #pragma unroll
      for (int m = 0; m < 2; ++m)
        p2[m] = __builtin_amdgcn_mfma_f32_16x16x32_bf16(aM[m], bW, p2[m], 0, 0, 0);
    }
    __syncthreads();
  }

  // LN2 epilogue (+b2 + h1res)
  {
    float bsv = b2[gc];
    #pragma unroll
    for (int m = 0; m < 2; ++m)
      #pragma unroll
      for (int r = 0; r < 4; ++r)
        p2[m][r] += bsv + h1res[m][r];
  }
  #pragma unroll
  for (int m = 0; m < 2; ++m)
    #pragma unroll
    for (int r = 0; r < 4; ++r) {
      float sm = p2[m][r];
      float sq = p2[m][r] * p2[m][r];
      #pragma unroll
      for (int msk = 1; msk <= 8; msk <<= 1) {
        sm += __shfl_xor(sm, msk);
        sq += __shfl_xor(sq, msk);
      }
      if (lr == 0) {
        int row = m * 16 + hi * 4 + r;
        lnred[row * 16 + wv * 2]     = sm;
        lnred[row * 16 + wv * 2 + 1] = sq;
      }
    }
  __syncthreads();
  {
    float g2v = lng[gc], bb2 = lnbv[gc];
    #pragma unroll
    for (int m = 0; m < 2; ++m)
      #pragma unroll
      for (int r = 0; r < 4; ++r) {
        int row = m * 16 + hi * 4 + r;
        int gr = mbase + row;
        float sm = 0.f, sq = 0.f;
        #pragma unroll
        for (int w = 0; w < 8; ++w) {
          sm += lnred[row * 16 + w * 2];
          sq += lnred[row * 16 + w * 2 + 1];
        }
        float mu = sm * (1.f / 128.f);
        float var = fmaxf(sq * (1.f / 128.f) - mu * mu, 0.f);
        float rstd = rsqrtf(var + LN_EPS);
        if (gr < M)
          outp[(size_t)gr * 128 + gc] = (p2[m][r] - mu) * rstd * g2v + bb2;
      }
  }
}

// ---------------- edge-softmax attention: fixed-max + packed-f32 (r14 proven) ----
__global__ __launch_bounds__(256) void k_attn(
    const ushort* __restrict__ q, const ushort* __restrict__ kv,
    const int* __restrict__ off, const int* __restrict__ csr,
    ushort* __restrict__ sav, int n)
{
  int node = blockIdx.x * 4 + (threadIdx.x >> 6);
  int lane = threadIdx.x & 63;
  if (node >= n) return;
  const int g = lane >> 3, sl = lane & 7;

  const ushort* qr = q + (size_t)node * 128 + sl * 16;
  uint4 qw0 = *reinterpret_cast<const uint4*>(qr);
  uint4 qw1 = *reinterpret_cast<const uint4*>(qr + 8);
  f32x2 qv[8];
  qv[0] = upk2(qw0.x); qv[1] = upk2(qw0.y); qv[2] = upk2(qw0.z); qv[3] = upk2(qw0.w);
  qv[4] = upk2(qw1.x); qv[5] = upk2(qw1.y); qv[6] = upk2(qw1.z); qv[7] = upk2(qw1.w);

  int b = off[node], e = off[node + 1];
  float s = 0.f;
  f32x2 a2[8] = {};
  int nIt = (e - b + 7) >> 3;
  int idx = b + g;
  int sn = (b < e) ? csr[min(idx, e - 1)] : 0;

  for (int i = 0; i < nIt; ++i) {
    bool act = idx < e;
    const ushort* kr = kv + (size_t)sn * 256 + sl * 16;
    uint4 kw0 = *reinterpret_cast<const uint4*>(kr);
    uint4 kw1 = *reinterpret_cast<const uint4*>(kr + 8);
    uint4 vw0 = *reinterpret_cast<const uint4*>(kr + 128);
    uint4 vw1 = *reinterpret_cast<const uint4*>(kr + 136);
    idx += 8;
    if (i + 1 < nIt) sn = csr[min(idx, e - 1)];

    f32x2 acc = qv[0] * upk2(kw0.x);
    acc += qv[1] * upk2(kw0.y);
    acc += qv[2] * upk2(kw0.z);
    acc += qv[3] * upk2(kw0.w);
    acc += qv[4] * upk2(kw1.x);
    acc += qv[5] * upk2(kw1.y);
    acc += qv[6] * upk2(kw1.z);
    acc += qv[7] * upk2(kw1.w);
    float p = acc[0] + acc[1];
    float u = fminf(fmaxf(p * 0.25f, -CLAMP_V), CLAMP_V);
    float w = __expf(u - CLAMP_V);
    w = act ? w : 0.f;
    s += w;
    f32x2 w2v; w2v[0] = w; w2v[1] = w;
    a2[0] += w2v * upk2(vw0.x);
    a2[1] += w2v * upk2(vw0.y);
    a2[2] += w2v * upk2(vw0.z);
    a2[3] += w2v * upk2(vw0.w);
    a2[4] += w2v * upk2(vw1.x);
    a2[5] += w2v * upk2(vw1.y);
    a2[6] += w2v * upk2(vw1.z);
    a2[7] += w2v * upk2(vw1.w);
  }

  #pragma unroll
  for (int msk = 8; msk <= 32; msk <<= 1) {
    s += __shfl_xor(s, msk);
    #pragma unroll
    for (int j = 0; j < 8; ++j) {
      a2[j][0] += __shfl_xor(a2[j][0], msk);
      a2[j][1] += __shfl_xor(a2[j][1], msk);
    }
  }

  float inv = (s > 0.f) ? 1.f / s : 0.f;
  if (g == 0) {
    uint w[8];
    #pragma unroll
    for (int j = 0; j < 8; ++j)
      w[j] = (uint)f2b(a2[j][0] * inv) | ((uint)f2b(a2[j][1] * inv) << 16);
    ushort* outp = sav + (size_t)node * 128 + sl * 16;
    uint4 o0 = {w[0], w[1], w[2], w[3]};
    uint4 o1 = {w[4], w[5], w[6], w[7]};
    *reinterpret_cast<uint4*>(outp) = o0;
    *reinterpret_cast<uint4*>(outp + 8) = o1;
  }
}

extern "C" void kernel_launch(void* const* d_in, const int* in_sizes, int n_in,
                              void* d_out, int out_size, void* d_ws, size_t ws_size,
                              hipStream_t stream)
{
  const float* feat = (const float*)d_in[0];
  const int*   src  = (const int*)d_in[1];
  const int*   dst  = (const int*)d_in[2];
  const float* Wq   = (const float*)d_in[3];
  const float* Wk   = (const float*)d_in[4];
  const float* Wv   = (const float*)d_in[5];
  const float* Wo   = (const float*)d_in[6];
  const float* ln1g = (const float*)d_in[7];
  const float* ln1b = (const float*)d_in[8];
  const float* W1   = (const float*)d_in[9];
  const float* b1   = (const float*)d_in[10];
  const float* W2   = (const float*)d_in[11];
  const float* b2   = (const float*)d_in[12];
  const float* ln2g = (const float*)d_in[13];
  const float* ln2b = (const float*)d_in[14];
  float* out = (float*)d_out;

  const int N = in_sizes[0] / DM;
  const int E = in_sizes[1];
  const size_t NB = (size_t)N;

  char* wsb = (char*)d_ws;
  ushort* q_bf    = (ushort*)wsb;
  ushort* kv_bf   = (ushort*)(wsb + NB * 256);
  ushort* sav_bf  = (ushort*)(wsb + NB * 768);
  ushort* h1b     = (ushort*)(wsb + NB * 1536);
  ushort* feat_bf = (ushort*)(wsb + NB * 1792);
  ushort* wbf     = (ushort*)(wsb + NB * 2048);
  ushort* wqkv_bf = wbf;
  ushort* wo_bf   = wbf + 49152;
  ushort* w1_bf   = wbf + 65536;
  ushort* w2_bf   = wbf + 131072;
  int* ib  = (int*)(wbf + 196608);
  int* deg = ib;
  int* cur = ib + N;
  int* off = ib + 2 * N;
  int* csr = ib + 3 * N + 1;

  hipMemsetAsync(deg, 0, (size_t)N * sizeof(int), stream);

  int nf4 = N * DM / 4;
  int castBlocks = (nf4 + 49152 + 255) / 256;
  int cntBlocks = (E + 255) / 256;
  k_prep<<<castBlocks + cntBlocks, 256, 0, stream>>>(
      feat, Wq, Wk, Wv, Wo, W1, W2, feat_bf, wbf, dst, deg, nf4, castBlocks, E);

  int nbk = (N + SC_EPB - 1) / SC_EPB;
  k_scan<<<nbk, 256, 0, stream>>>(deg, off, cur, N, E);
  k_scatter<<<cntBlocks, 256, 0, stream>>>(src, dst, off, cur, csr, E);

  const int nT = (N + 127) / 128;   // 313
  k_qkv<<<dim3(3, nT), 512, 0, stream>>>(feat_bf, wqkv_bf, q_bf, kv_bf, N);

  int nb4 = (N + 3) / 4;
  k_attn<<<nb4, 256, 0, stream>>>(q_bf, kv_bf, off, csr, sav_bf, N);

  // h1b = LN1(sav @ Wo^T + feat)
  k_mmT<<<dim3(1, nT), 512, 0, stream>>>(sav_bf, wo_bf, feat, ln1g, ln1b, h1b, N);

  // fused FFN: out = LN2(relu(h1b@W1^T+b1)@W2^T + b2 + h1res)
  const int nF = (N + 31) / 32;     // 1250
  k_ffn<<<nF, 512, 0, stream>>>(
      h1b, w1_bf, b1, w2_bf, b2, ln2g, ln2b, out, N);
}

// Round 17
// 189.317 us; speedup vs baseline: 1.0398x; 1.0070x over previous
//
#include <hip/hip_runtime.h>

#define DM 128
#define DFF 512
#define CLAMP_V 5.0f
#define LN_EPS 1e-5f

typedef __attribute__((ext_vector_type(8))) short bf16x8;
typedef __attribute__((ext_vector_type(4))) float f32x4;
typedef __attribute__((ext_vector_type(2))) float f32x2;

__device__ __forceinline__ float b2f(ushort u) {
  union { uint u; float f; } x; x.u = ((uint)u) << 16; return x.f;
}
__device__ __forceinline__ ushort f2b(float f) {
  union { float f; uint u; } x; x.f = f;
  uint r = x.u + 0x7FFFu + ((x.u >> 16) & 1u);
  return (ushort)(r >> 16);
}
__device__ __forceinline__ f32x2 upk2(uint w) {
  union { uint u; float f; } a, b;
  a.u = w << 16; b.u = w & 0xFFFF0000u;
  f32x2 r; r[0] = a.f; r[1] = b.f; return r;
}

// ---------------- fused prep: feat cast + weight cast + degree count ----------------
__global__ void k_prep(const float* __restrict__ feat,
                       const float* __restrict__ wq, const float* __restrict__ wk,
                       const float* __restrict__ wv, const float* __restrict__ wo,
                       const float* __restrict__ w1, const float* __restrict__ w2,
                       ushort* __restrict__ feat_bf, ushort* __restrict__ wbf,
                       const int* __restrict__ dst, int* __restrict__ deg,
                       int nf4, int castBlocks, int E) {
  if ((int)blockIdx.x >= castBlocks) {
    int e = ((int)blockIdx.x - castBlocks) * 256 + threadIdx.x;
    if (e < E) atomicAdd(&deg[dst[e]], 1);
    return;
  }
  int i = blockIdx.x * 256 + threadIdx.x;
  if (i < nf4) {
    float4 v = *reinterpret_cast<const float4*>(feat + i * 4);
    ushort4 o; o.x = f2b(v.x); o.y = f2b(v.y); o.z = f2b(v.z); o.w = f2b(v.w);
    *reinterpret_cast<ushort4*>(feat_bf + i * 4) = o;
    return;
  }
  int i4 = (i - nf4) * 4;
  if (i4 >= 196608) return;
  const float* s; int o;
  if      (i4 < 16384)  { s = wq; o = i4; }
  else if (i4 < 32768)  { s = wk; o = i4 - 16384; }
  else if (i4 < 49152)  { s = wv; o = i4 - 32768; }
  else if (i4 < 65536)  { s = wo; o = i4 - 49152; }
  else if (i4 < 131072) { s = w1; o = i4 - 65536; }
  else                  { s = w2; o = i4 - 131072; }
  float4 v = *reinterpret_cast<const float4*>(s + o);
  ushort4 u; u.x = f2b(v.x); u.y = f2b(v.y); u.z = f2b(v.z); u.w = f2b(v.w);
  *reinterpret_cast<ushort4*>(wbf + i4) = u;
}

#define SC_EPB 1024

// single-kernel exclusive scan; also zeroes cur, writes off[n]=E
__global__ __launch_bounds__(256) void k_scan(const int* __restrict__ deg,
                                              int* __restrict__ off,
                                              int* __restrict__ cur,
                                              int n, int E) {
  __shared__ int sh[256];
  __shared__ int wsum[4];
  const int t = threadIdx.x;
  const int bstart = blockIdx.x * SC_EPB;

  int gs = 0;
  for (int base = t * 4; base < bstart; base += SC_EPB) {
    int4 v = *reinterpret_cast<const int4*>(deg + base);
    gs += v.x + v.y + v.z + v.w;
  }
  #pragma unroll
  for (int m = 1; m < 64; m <<= 1) gs += __shfl_xor(gs, m);
  if ((t & 63) == 0) wsum[t >> 6] = gs;
  __syncthreads();
  int gadd = wsum[0] + wsum[1] + wsum[2] + wsum[3];
  __syncthreads();

  int base = bstart + t * 4;
  int4 v = {0, 0, 0, 0};
  if (base + 3 < n) {
    v = *reinterpret_cast<const int4*>(deg + base);
  } else {
    if (base     < n) v.x = deg[base];
    if (base + 1 < n) v.y = deg[base + 1];
    if (base + 2 < n) v.z = deg[base + 2];
    if (base + 3 < n) v.w = deg[base + 3];
  }
  int s = v.x + v.y + v.z + v.w;
  sh[t] = s;
  __syncthreads();
  #pragma unroll
  for (int d = 1; d < 256; d <<= 1) {
    int x = 0;
    if (t >= d) x = sh[t - d];
    __syncthreads();
    sh[t] += x;
    __syncthreads();
  }
  int ex = sh[t] - s + gadd;
  if (base + 3 < n) {
    int4 o; o.x = ex; o.y = ex + v.x; o.z = ex + v.x + v.y; o.w = ex + v.x + v.y + v.z;
    *reinterpret_cast<int4*>(off + base) = o;
    int4 z = {0, 0, 0, 0};
    *reinterpret_cast<int4*>(cur + base) = z;
  } else {
    if (base     < n) { off[base]     = ex;                    cur[base]     = 0; }
    if (base + 1 < n) { off[base + 1] = ex + v.x;              cur[base + 1] = 0; }
    if (base + 2 < n) { off[base + 2] = ex + v.x + v.y;        cur[base + 2] = 0; }
    if (base + 3 < n) { off[base + 3] = ex + v.x + v.y + v.z;  cur[base + 3] = 0; }
  }
  if (blockIdx.x == 0 && t == 0) off[n] = E;
}

// standalone scatter (0 LDS, full occupancy)
__global__ void k_scatter(const int* __restrict__ src, const int* __restrict__ dst,
                          const int* __restrict__ off, int* __restrict__ cur,
                          int* __restrict__ csr, int E) {
  int e = blockIdx.x * blockDim.x + threadIdx.x;
  if (e < E) {
    int d = dst[e];
    int p = off[d] + atomicAdd(&cur[d], 1);
    csr[p] = src[e];
  }
}

// =====================================================================
// k_qkv: one-tile-per-block GEMM, QKV split output. 512 thr, 2 blk/CU.
// =====================================================================
__global__ __launch_bounds__(512, 2) void k_qkv(
    const ushort* __restrict__ A, const ushort* __restrict__ W,
    ushort* __restrict__ Cb, ushort* __restrict__ Cb2, int M)
{
  __shared__ ushort As[128 * 128];
  __shared__ ushort Bs[128 * 128];

  const int tid = threadIdx.x;
  const int wv = tid >> 6, ln = tid & 63;
  const int bnb = blockIdx.x;
  const int mbase = blockIdx.y * 128;
  const int wrow = (wv >> 2) * 64, wcol = (wv & 3) * 32;
  const int o_base = tid * 16;

  #pragma unroll
  for (int is = 0; is < 4; ++is) {
    int o = is * 8192 + o_base;
    int row = o >> 8;
    int c = ((o >> 4) & 15) ^ (row & 15);
    int gr = min(mbase + row, M - 1);
    const ushort* sA = A + (size_t)gr * 128 + c * 8;
    __builtin_amdgcn_global_load_lds(
        (const __attribute__((address_space(1))) void*)sA,
        (__attribute__((address_space(3))) void*)((char*)As + is * 8192 + wv * 1024),
        16, 0, 0);
    const ushort* sB = W + (size_t)(bnb * 128 + row) * 128 + c * 8;
    __builtin_amdgcn_global_load_lds(
        (const __attribute__((address_space(1))) void*)sB,
        (__attribute__((address_space(3))) void*)((char*)Bs + is * 8192 + wv * 1024),
        16, 0, 0);
  }
  __syncthreads();

  f32x4 acc[4][2] = {};
  const char* AsB = (const char*)As;
  const char* BsB = (const char*)Bs;
  #pragma unroll
  for (int kk = 0; kk < 4; ++kk) {
    bf16x8 af[4], bfr[2];
    #pragma unroll
    for (int m = 0; m < 4; ++m) {
      int r = wrow + m * 16 + (ln & 15);
      int c = kk * 4 + (ln >> 4);
      af[m] = *reinterpret_cast<const bf16x8*>(AsB + r * 256 + ((c ^ (r & 15)) << 4));
    }
    #pragma unroll
    for (int n = 0; n < 2; ++n) {
      int r = wcol + n * 16 + (ln & 15);
      int c = kk * 4 + (ln >> 4);
      bfr[n] = *reinterpret_cast<const bf16x8*>(BsB + r * 256 + ((c ^ (r & 15)) << 4));
    }
    #pragma unroll
    for (int m = 0; m < 4; ++m)
      #pragma unroll
      for (int n = 0; n < 2; ++n)
        acc[m][n] = __builtin_amdgcn_mfma_f32_16x16x32_bf16(af[m], bfr[n], acc[m][n], 0, 0, 0);
  }

  #pragma unroll
  for (int m = 0; m < 4; ++m) {
    int gr0 = mbase + wrow + m * 16 + (ln >> 4) * 4;
    #pragma unroll
    for (int n = 0; n < 2; ++n) {
      int gcl = wcol + n * 16 + (ln & 15);
      #pragma unroll
      for (int r = 0; r < 4; ++r) {
        int gr = gr0 + r;
        if (gr >= M) continue;
        float v = acc[m][n][r];
        if (bnb == 0) Cb[(size_t)gr * 128 + gcl] = f2b(v);
        else          Cb2[(size_t)gr * 256 + (bnb - 1) * 128 + gcl] = f2b(v);
      }
    }
  }
}

// =====================================================================
// k_attn: edge-softmax attention (fixed-max, packed-f32) FUSED with
// wo-GEMM + LN1. 512 thr / 8 waves / 32 nodes per block; each wave
// serially processes 4 nodes, results -> swizzled LDS tile savt[32][128];
// then ph0-style Wo MFMA (+feat residual) + register-LN1 -> h1b (bf16).
// LDS = savt 8KB + wot 32KB + lnred 2KB = 42KB -> 3 blocks/CU.
// =====================================================================
__global__ __launch_bounds__(512, 2) void k_attn(
    const ushort* __restrict__ q, const ushort* __restrict__ kv,
    const int* __restrict__ off, const int* __restrict__ csr,
    const float* __restrict__ feat, const ushort* __restrict__ wo,
    const float* __restrict__ ln1g, const float* __restrict__ ln1b,
    ushort* __restrict__ h1b, int n)
{
  __shared__ ushort savt[32 * 128];   // 256B rows, 16-chunk XOR swizzle
  __shared__ ushort wot[128 * 128];   // k_mmT Bs layout
  __shared__ float lnred[32 * 16];

  const int tid = threadIdx.x;
  const int wv = tid >> 6, ln = tid & 63;
  const int lr = ln & 15, hi = ln >> 4;
  const int g = ln >> 3, sl = ln & 7;
  const int mbase = blockIdx.x * 32;

  // stage Wo (32KB, completes by the post-attn barrier's vmcnt drain)
  #pragma unroll
  for (int is = 0; is < 4; ++is) {
    int o = is * 8192 + tid * 16;
    int r = o >> 8;
    int c = ((o >> 4) & 15) ^ (r & 15);
    const ushort* s = wo + (size_t)r * 128 + c * 8;
    __builtin_amdgcn_global_load_lds(
        (const __attribute__((address_space(1))) void*)s,
        (__attribute__((address_space(3))) void*)((char*)wot + is * 8192 + wv * 1024),
        16, 0, 0);
  }

  // ---- attention: wave wv processes nodes mbase + wv*4 + i ----
  for (int i = 0; i < 4; ++i) {
    int node = mbase + wv * 4 + i;
    if (node < n) {
      const ushort* qr = q + (size_t)node * 128 + sl * 16;
      uint4 qw0 = *reinterpret_cast<const uint4*>(qr);
      uint4 qw1 = *reinterpret_cast<const uint4*>(qr + 8);
      f32x2 qv[8];
      qv[0] = upk2(qw0.x); qv[1] = upk2(qw0.y); qv[2] = upk2(qw0.z); qv[3] = upk2(qw0.w);
      qv[4] = upk2(qw1.x); qv[5] = upk2(qw1.y); qv[6] = upk2(qw1.z); qv[7] = upk2(qw1.w);

      int b = off[node], e = off[node + 1];
      float s = 0.f;
      f32x2 a2[8] = {};
      int nIt = (e - b + 7) >> 3;
      int idx = b + g;
      int sn = (b < e) ? csr[min(idx, e - 1)] : 0;

      for (int it = 0; it < nIt; ++it) {
        bool act = idx < e;
        const ushort* kr = kv + (size_t)sn * 256 + sl * 16;
        uint4 kw0 = *reinterpret_cast<const uint4*>(kr);
        uint4 kw1 = *reinterpret_cast<const uint4*>(kr + 8);
        uint4 vw0 = *reinterpret_cast<const uint4*>(kr + 128);
        uint4 vw1 = *reinterpret_cast<const uint4*>(kr + 136);
        idx += 8;
        if (it + 1 < nIt) sn = csr[min(idx, e - 1)];

        f32x2 acc = qv[0] * upk2(kw0.x);
        acc += qv[1] * upk2(kw0.y);
        acc += qv[2] * upk2(kw0.z);
        acc += qv[3] * upk2(kw0.w);
        acc += qv[4] * upk2(kw1.x);
        acc += qv[5] * upk2(kw1.y);
        acc += qv[6] * upk2(kw1.z);
        acc += qv[7] * upk2(kw1.w);
        float p = acc[0] + acc[1];
        float u = fminf(fmaxf(p * 0.25f, -CLAMP_V), CLAMP_V);
        float w = __expf(u - CLAMP_V);
        w = act ? w : 0.f;
        s += w;
        f32x2 w2v; w2v[0] = w; w2v[1] = w;
        a2[0] += w2v * upk2(vw0.x);
        a2[1] += w2v * upk2(vw0.y);
        a2[2] += w2v * upk2(vw0.z);
        a2[3] += w2v * upk2(vw0.w);
        a2[4] += w2v * upk2(vw1.x);
        a2[5] += w2v * upk2(vw1.y);
        a2[6] += w2v * upk2(vw1.z);
        a2[7] += w2v * upk2(vw1.w);
      }

      #pragma unroll
      for (int msk = 8; msk <= 32; msk <<= 1) {
        s += __shfl_xor(s, msk);
        #pragma unroll
        for (int j = 0; j < 8; ++j) {
          a2[j][0] += __shfl_xor(a2[j][0], msk);
          a2[j][1] += __shfl_xor(a2[j][1], msk);
        }
      }

      float inv = (s > 0.f) ? 1.f / s : 0.f;
      if (g == 0) {
        uint w[8];
        #pragma unroll
        for (int j = 0; j < 8; ++j)
          w[j] = (uint)f2b(a2[j][0] * inv) | ((uint)f2b(a2[j][1] * inv) << 16);
        int nl = wv * 4 + i;
        int c0 = sl * 2, c1 = sl * 2 + 1;
        uint4 o0 = {w[0], w[1], w[2], w[3]};
        uint4 o1 = {w[4], w[5], w[6], w[7]};
        *reinterpret_cast<uint4*>((char*)savt + nl * 256 + ((c0 ^ (nl & 15)) << 4)) = o0;
        *reinterpret_cast<uint4*>((char*)savt + nl * 256 + ((c1 ^ (nl & 15)) << 4)) = o1;
      }
    }
  }
  __syncthreads();   // savt complete; wot DMA drained

  // ---- Wo GEMM [32][128]: h1 = LN1(savt @ Wo^T + feat) ----
  const int gc = wv * 16 + lr;
  f32x4 p0[2] = {};
  #pragma unroll
  for (int kk = 0; kk < 4; ++kk) {
    int c = kk * 4 + hi;
    int wr = wv * 16 + lr;
    bf16x8 bWo = *reinterpret_cast<const bf16x8*>((char*)wot + wr * 256 + ((c ^ (wr & 15)) << 4));
    bf16x8 aS[2];
    #pragma unroll
    for (int m = 0; m < 2; ++m) {
      int r = m * 16 + lr;
      aS[m] = *reinterpret_cast<const bf16x8*>((char*)savt + r * 256 + ((c ^ (r & 15)) << 4));
    }
    #pragma unroll
    for (int m = 0; m < 2; ++m)
      p0[m] = __builtin_amdgcn_mfma_f32_16x16x32_bf16(aS[m], bWo, p0[m], 0, 0, 0);
  }
  // +feat residual
  #pragma unroll
  for (int m = 0; m < 2; ++m)
    #pragma unroll
    for (int r = 0; r < 4; ++r) {
      int gr = mbase + m * 16 + hi * 4 + r;
      p0[m][r] += feat[(size_t)min(gr, n - 1) * 128 + gc];
    }
  // LN1
  #pragma unroll
  for (int m = 0; m < 2; ++m)
    #pragma unroll
    for (int r = 0; r < 4; ++r) {
      float sm = p0[m][r];
      float sq = p0[m][r] * p0[m][r];
      #pragma unroll
      for (int msk = 1; msk <= 8; msk <<= 1) {
        sm += __shfl_xor(sm, msk);
        sq += __shfl_xor(sq, msk);
      }
      if (lr == 0) {
        int row = m * 16 + hi * 4 + r;
        lnred[row * 16 + wv * 2]     = sm;
        lnred[row * 16 + wv * 2 + 1] = sq;
      }
    }
  __syncthreads();
  {
    float g1v = ln1g[gc], bb1 = ln1b[gc];
    #pragma unroll
    for (int m = 0; m < 2; ++m)
      #pragma unroll
      for (int r = 0; r < 4; ++r) {
        int row = m * 16 + hi * 4 + r;
        int gr = mbase + row;
        float sm = 0.f, sq = 0.f;
        #pragma unroll
        for (int w = 0; w < 8; ++w) {
          sm += lnred[row * 16 + w * 2];
          sq += lnred[row * 16 + w * 2 + 1];
        }
        float mu = sm * (1.f / 128.f);
        float var = fmaxf(sq * (1.f / 128.f) - mu * mu, 0.f);
        float rstd = rsqrtf(var + LN_EPS);
        if (gr < n)
          h1b[(size_t)gr * 128 + gc] = f2b((p0[m][r] - mu) * rstd * g1v + bb1);
      }
  }
}

// =====================================================================
// k_ffn: 32 rows/block, 66KB LDS -> 2 blocks/CU (round-16 proven).
// =====================================================================
__global__ __launch_bounds__(512, 4) void k_ffn(
    const ushort* __restrict__ h1b,
    const ushort* __restrict__ w1, const float* __restrict__ b1,
    const ushort* __restrict__ w2, const float* __restrict__ b2,
    const float* __restrict__ lng, const float* __restrict__ lnbv,
    float* __restrict__ outp, int M)
{
  __shared__ ushort mid[32 * 512];
  __shared__ ushort wbuf[2][128 * 64];
  __shared__ float lnred[32 * 16];

  const int tid = threadIdx.x;
  const int wv = tid >> 6, ln = tid & 63;
  const int lr = ln & 15, hi = ln >> 4;
  const int mbase = blockIdx.x * 32;
  const int gc = wv * 16 + lr;

  auto STG64 = [&](const ushort* srcBase, int srcLd, int colOff, char* dstLds) {
    #pragma unroll
    for (int is = 0; is < 2; ++is) {
      int o = is * 8192 + tid * 16;
      int r = o >> 7;
      int c = ((o >> 4) & 7) ^ (r & 7);
      const ushort* s = srcBase + (size_t)r * srcLd + colOff + c * 8;
      __builtin_amdgcn_global_load_lds(
          (const __attribute__((address_space(1))) void*)s,
          (__attribute__((address_space(3))) void*)(dstLds + is * 8192 + wv * 1024),
          16, 0, 0);
    }
  };

  {
    int o = tid * 16;
    int r = o >> 8;
    int c = ((o >> 4) & 15) ^ (r & 15);
    int gr = min(mbase + r, M - 1);
    const ushort* s = h1b + (size_t)gr * 128 + c * 8;
    __builtin_amdgcn_global_load_lds(
        (const __attribute__((address_space(1))) void*)s,
        (__attribute__((address_space(3))) void*)((char*)mid + wv * 1024),
        16, 0, 0);
  }
  STG64(w1, 128, 0, (char*)wbuf[0]);
  __syncthreads();

  f32x4 p1[4][2] = {};
  const char* hB = (const char*)mid;
  #pragma unroll
  for (int g = 0; g < 4; ++g) {
    #pragma unroll
    for (int kh = 0; kh < 2; ++kh) {
      const int step = g * 2 + kh;
      if (step < 7) {
        int ns = step + 1;
        STG64(w1 + (size_t)(ns >> 1) * 128 * 128, 128, (ns & 1) * 64, (char*)wbuf[ns & 1]);
      } else {
        STG64(w2, 512, 0, (char*)wbuf[0]);
      }
      const char* wB = (const char*)wbuf[step & 1];
      #pragma unroll
      for (int kk = 0; kk < 2; ++kk) {
        int ct = kk * 4 + hi;
        int cg = kh * 8 + ct;
        int wr = wv * 16 + lr;
        bf16x8 aW = *reinterpret_cast<const bf16x8*>(wB + wr * 128 + ((ct ^ (wr & 7)) << 4));
        bf16x8 bH[2];
        #pragma unroll
        for (int hj = 0; hj < 2; ++hj) {
          int r = hj * 16 + lr;
          bH[hj] = *reinterpret_cast<const bf16x8*>(hB + r * 256 + ((cg ^ (r & 15)) << 4));
        }
        #pragma unroll
        for (int hj = 0; hj < 2; ++hj)
          p1[g][hj] = __builtin_amdgcn_mfma_f32_16x16x32_bf16(aW, bH[hj], p1[g][hj], 0, 0, 0);
      }
      __syncthreads();
    }
  }

  float h1res[2][4];
  {
    int chunk = gc >> 3;
    int sub = (gc & 7) * 2;
    #pragma unroll
    for (int m = 0; m < 2; ++m)
      #pragma unroll
      for (int r = 0; r < 4; ++r) {
        int row = m * 16 + hi * 4 + r;
        h1res[m][r] = b2f(*reinterpret_cast<const ushort*>(
            (const char*)mid + row * 256 + ((chunk ^ (row & 15)) << 4) + sub));
      }
  }
  __syncthreads();

  #pragma unroll
  for (int g = 0; g < 4; ++g) {
    int mc0 = g * 128 + wv * 16 + hi * 4;
    float4 bv = *reinterpret_cast<const float4*>(b1 + mc0);
    int chunk = mc0 >> 3;
    int sub = (mc0 & 7) * 2;
    #pragma unroll
    for (int hj = 0; hj < 2; ++hj) {
      int orow = hj * 16 + lr;
      ushort4 pk;
      pk.x = f2b(fmaxf(p1[g][hj][0] + bv.x, 0.f));
      pk.y = f2b(fmaxf(p1[g][hj][1] + bv.y, 0.f));
      pk.z = f2b(fmaxf(p1[g][hj][2] + bv.z, 0.f));
      pk.w = f2b(fmaxf(p1[g][hj][3] + bv.w, 0.f));
      char* dstp = (char*)mid + orow * 1024 + (((chunk & 63) ^ (orow & 15)) << 4) + sub;
      *reinterpret_cast<ushort4*>(dstp) = pk;
    }
  }
  __syncthreads();

  f32x4 p2[2] = {};
  #pragma unroll
  for (int kt = 0; kt < 8; ++kt) {
    if (kt < 7) STG64(w2, 512, (kt + 1) * 64, (char*)wbuf[(kt + 1) & 1]);
    const char* wB = (const char*)wbuf[kt & 1];
    #pragma unroll
    for (int kk = 0; kk < 2; ++kk) {
      int ct = kk * 4 + hi;
      int cm = kt * 8 + ct;
      int wr = wv * 16 + lr;
      bf16x8 bW = *reinterpret_cast<const bf16x8*>(wB + wr * 128 + ((ct ^ (wr & 7)) << 4));
      bf16x8 aM[2];
      #pragma unroll
      for (int m = 0; m < 2; ++m) {
        int r = m * 16 + lr;
        aM[m] = *reinterpret_cast<const bf16x8*>((const char*)mid + r * 1024 + (((cm & 63) ^ (r & 15)) << 4));
      }
      #pragma unroll
      for (int m = 0; m < 2; ++m)
        p2[m] = __builtin_amdgcn_mfma_f32_16x16x32_bf16(aM[m], bW, p2[m], 0, 0, 0);
    }
    __syncthreads();
  }

  {
    float bsv = b2[gc];
    #pragma unroll
    for (int m = 0; m < 2; ++m)
      #pragma unroll
      for (int r = 0; r < 4; ++r)
        p2[m][r] += bsv + h1res[m][r];
  }
  #pragma unroll
  for (int m = 0; m < 2; ++m)
    #pragma unroll
    for (int r = 0; r < 4; ++r) {
      float sm = p2[m][r];
      float sq = p2[m][r] * p2[m][r];
      #pragma unroll
      for (int msk = 1; msk <= 8; msk <<= 1) {
        sm += __shfl_xor(sm, msk);
        sq += __shfl_xor(sq, msk);
      }
      if (lr == 0) {
        int row = m * 16 + hi * 4 + r;
        lnred[row * 16 + wv * 2]     = sm;
        lnred[row * 16 + wv * 2 + 1] = sq;
      }
    }
  __syncthreads();
  {
    float g2v = lng[gc], bb2 = lnbv[gc];
    #pragma unroll
    for (int m = 0; m < 2; ++m)
      #pragma unroll
      for (int r = 0; r < 4; ++r) {
        int row = m * 16 + hi * 4 + r;
        int gr = mbase + row;
        float sm = 0.f, sq = 0.f;
        #pragma unroll
        for (int w = 0; w < 8; ++w) {
          sm += lnred[row * 16 + w * 2];
          sq += lnred[row * 16 + w * 2 + 1];
        }
        float mu = sm * (1.f / 128.f);
        float var = fmaxf(sq * (1.f / 128.f) - mu * mu, 0.f);
        float rstd = rsqrtf(var + LN_EPS);
        if (gr < M)
          outp[(size_t)gr * 128 + gc] = (p2[m][r] - mu) * rstd * g2v + bb2;
      }
  }
}

extern "C" void kernel_launch(void* const* d_in, const int* in_sizes, int n_in,
                              void* d_out, int out_size, void* d_ws, size_t ws_size,
                              hipStream_t stream)
{
  const float* feat = (const float*)d_in[0];
  const int*   src  = (const int*)d_in[1];
  const int*   dst  = (const int*)d_in[2];
  const float* Wq   = (const float*)d_in[3];
  const float* Wk   = (const float*)d_in[4];
  const float* Wv   = (const float*)d_in[5];
  const float* Wo   = (const float*)d_in[6];
  const float* ln1g = (const float*)d_in[7];
  const float* ln1b = (const float*)d_in[8];
  const float* W1   = (const float*)d_in[9];
  const float* b1   = (const float*)d_in[10];
  const float* W2   = (const float*)d_in[11];
  const float* b2   = (const float*)d_in[12];
  const float* ln2g = (const float*)d_in[13];
  const float* ln2b = (const float*)d_in[14];
  float* out = (float*)d_out;

  const int N = in_sizes[0] / DM;
  const int E = in_sizes[1];
  const size_t NB = (size_t)N;

  char* wsb = (char*)d_ws;
  ushort* q_bf    = (ushort*)wsb;
  ushort* kv_bf   = (ushort*)(wsb + NB * 256);
  ushort* h1b     = (ushort*)(wsb + NB * 1536);
  ushort* feat_bf = (ushort*)(wsb + NB * 1792);
  ushort* wbf     = (ushort*)(wsb + NB * 2048);
  ushort* wqkv_bf = wbf;
  ushort* wo_bf   = wbf + 49152;
  ushort* w1_bf   = wbf + 65536;
  ushort* w2_bf   = wbf + 131072;
  int* ib  = (int*)(wbf + 196608);
  int* deg = ib;
  int* cur = ib + N;
  int* off = ib + 2 * N;
  int* csr = ib + 3 * N + 1;

  hipMemsetAsync(deg, 0, (size_t)N * sizeof(int), stream);

  int nf4 = N * DM / 4;
  int castBlocks = (nf4 + 49152 + 255) / 256;
  int cntBlocks = (E + 255) / 256;
  k_prep<<<castBlocks + cntBlocks, 256, 0, stream>>>(
      feat, Wq, Wk, Wv, Wo, W1, W2, feat_bf, wbf, dst, deg, nf4, castBlocks, E);

  int nbk = (N + SC_EPB - 1) / SC_EPB;
  k_scan<<<nbk, 256, 0, stream>>>(deg, off, cur, N, E);
  k_scatter<<<cntBlocks, 256, 0, stream>>>(src, dst, off, cur, csr, E);

  const int nT = (N + 127) / 128;   // 313
  k_qkv<<<dim3(3, nT), 512, 0, stream>>>(feat_bf, wqkv_bf, q_bf, kv_bf, N);

  // attn + wo + LN1 fused -> h1b
  const int nA = (N + 31) / 32;     // 1250
  k_attn<<<nA, 512, 0, stream>>>(
      q_bf, kv_bf, off, csr, feat, wo_bf, ln1g, ln1b, h1b, N);

  // fused FFN: out = LN2(relu(h1b@W1^T+b1)@W2^T + b2 + h1res)
  const int nF = (N + 31) / 32;     // 1250
  k_ffn<<<nF, 512, 0, stream>>>(
      h1b, w1_bf, b1, w2_bf, b2, ln2g, ln2b, out, N);
}